// Round 4
// baseline (944.821 us; speedup 1.0000x reference)
//
#include <hip/hip_runtime.h>
#include <stdint.h>
#include <math.h>

// Problem constants (from reference)
#define T_STEPS 128
#define NB      128
#define HID     64
#define CONVOUT 4096
#define NSUB    5
#define SUBSZ   14      // A+B+C = 5+3+6
#define NG      90      // A*B*C
#define STATE   99
#define DIN     4111    // CONVOUT + 3*NSUB
#define WFCOLS  4125    // CONVOUT + 2*SUBSZ + 1
#define WBCOLS  4110    // CONVOUT + SUBSZ
#define NROWS   (T_STEPS * NB)   // 16384
#define GIXST   193              // GI_x row stride (192 gi cols + CX)

#define NEGINFF (-3.0e38f)

typedef __attribute__((ext_vector_type(2))) float f32x2;

#define SEL5(a,b,c,d,e,ix) ((ix)==0?(a):(ix)==1?(b):(ix)==2?(c):(ix)==3?(d):(e))
#define SEL3(a,b,c,ix)     ((ix)==0?(a):(ix)==1?(b):(c))
#define SEL6(a,b,c,d,e,f,ix) ((ix)==0?(a):(ix)==1?(b):(ix)==2?(c):(ix)==3?(d):(ix)==4?(e):(f))

// ---------------- Threefry-2x32 (JAX-compatible) ----------------
__device__ __forceinline__ void tf2x32(unsigned k0, unsigned k1,
                                       unsigned x0, unsigned x1,
                                       unsigned &o0, unsigned &o1) {
  unsigned K0 = k0, K1 = k1, K2 = k0 ^ k1 ^ 0x1BD11BDAu;
  x0 += K0; x1 += K1;
  const int R0[4] = {13, 15, 26, 6};
  const int R1[4] = {17, 29, 16, 24};
  #pragma unroll
  for (int j = 0; j < 4; ++j) { x0 += x1; x1 = (x1 << R0[j]) | (x1 >> (32 - R0[j])); x1 ^= x0; }
  x0 += K1; x1 += K2 + 1u;
  #pragma unroll
  for (int j = 0; j < 4; ++j) { x0 += x1; x1 = (x1 << R1[j]) | (x1 >> (32 - R1[j])); x1 ^= x0; }
  x0 += K2; x1 += K0 + 2u;
  #pragma unroll
  for (int j = 0; j < 4; ++j) { x0 += x1; x1 = (x1 << R0[j]) | (x1 >> (32 - R0[j])); x1 ^= x0; }
  x0 += K0; x1 += K1 + 3u;
  #pragma unroll
  for (int j = 0; j < 4; ++j) { x0 += x1; x1 = (x1 << R1[j]) | (x1 >> (32 - R1[j])); x1 ^= x0; }
  x0 += K1; x1 += K2 + 4u;
  #pragma unroll
  for (int j = 0; j < 4; ++j) { x0 += x1; x1 = (x1 << R0[j]) | (x1 >> (32 - R0[j])); x1 ^= x0; }
  x0 += K2; x1 += K0 + 5u;
  o0 = x0; o1 = x1;
}

__device__ __forceinline__ double bits_to_gumbel_d(unsigned bits) {
  float f = __uint_as_float((bits >> 9) | 0x3f800000u) - 1.0f;   // exact in f32
  const double tiny = (double)1.17549435e-38f;
  double u = fmax(tiny, (double)f + tiny);
  return -log(-log(u));
}

__device__ __forceinline__ float rlane(float v, int l) {
  return __int_as_float(__builtin_amdgcn_readlane(__float_as_int(v), l));
}

// DPP shifted copy: lanes without a source (or rows masked off) get `fill`.
template<int CTRL, int RM>
__device__ __forceinline__ float dpp_mv(float x, float fill) {
  return __int_as_float(__builtin_amdgcn_update_dpp(
      __float_as_int(fill), __float_as_int(x), CTRL, RM, 0xF, false));
}

// 4-way sum reduce (valid at lane 63)
__device__ __forceinline__ void dpp_sum4(float &a, float &b, float &c, float &d) {
  #define S4(C, RM) { a += dpp_mv<C,RM>(a,0.f); b += dpp_mv<C,RM>(b,0.f); \
                      c += dpp_mv<C,RM>(c,0.f); d += dpp_mv<C,RM>(d,0.f); }
  S4(0x111,0xF) S4(0x112,0xF) S4(0x114,0xF) S4(0x118,0xF) S4(0x142,0xA) S4(0x143,0xC)
  #undef S4
}

// (max, runner-up) pair reduce (valid at lane 63)
__device__ __forceinline__ void dpp_amax2(float &m1, float &m2) {
  #define A2(C, RM) { float o1 = dpp_mv<C,RM>(m1,NEGINFF), o2 = dpp_mv<C,RM>(m2,NEGINFF); \
    m2 = fmaxf(fmaxf(m2,o2), fminf(m1,o1)); m1 = fmaxf(m1,o1); }
  A2(0x111,0xF) A2(0x112,0xF) A2(0x114,0xF) A2(0x118,0xF) A2(0x142,0xA) A2(0x143,0xC)
  #undef A2
}

// single sum reduce, broadcast result to all lanes
__device__ __forceinline__ float dpp_sum_bcast(float v) {
  v += dpp_mv<0x111,0xF>(v, 0.f);
  v += dpp_mv<0x112,0xF>(v, 0.f);
  v += dpp_mv<0x114,0xF>(v, 0.f);
  v += dpp_mv<0x118,0xF>(v, 0.f);
  v += dpp_mv<0x142,0xA>(v, 0.f);
  v += dpp_mv<0x143,0xC>(v, 0.f);
  return rlane(v, 63);
}

// Barrier that waits LDS only (lgkmcnt(0)) — does NOT drain vmcnt.
__device__ __forceinline__ void bar_lds() {
  __asm__ volatile("" ::: "memory");
  __builtin_amdgcn_s_waitcnt(0xC07F);
  __builtin_amdgcn_s_barrier();
  __asm__ volatile("" ::: "memory");
}

// ---------------- K0: pack/transpose weights ----------------
__global__ void k_transpose(const float* __restrict__ Wf, const float* __restrict__ Wb,
                            float* __restrict__ Wt) {
  int idx = blockIdx.x * 256 + threadIdx.x;     // < 66*4096
  int c = idx >> 12;                            // 0..65
  int k = idx & 4095;
  float v = (c < 64) ? Wf[(size_t)c * WFCOLS + k] : Wb[(size_t)(c - 64) * WBCOLS + k];
  Wt[(size_t)k * 68 + c] = v;
}

// ---------------- K0b: Wt2[k][i] = Wih[i][k] (i<192) / Wc[k] (i==192) ----------------
__global__ void k_tr2(const float* __restrict__ Wih, const float* __restrict__ Wc,
                      float* __restrict__ Wt2) {
  int idx = blockIdx.x * 256 + threadIdx.x;
  if (idx >= 64 * GIXST) return;
  int k = idx / GIXST, i = idx - k * GIXST;
  Wt2[(size_t)k * 208 + i] = (i < 192) ? Wih[(size_t)i * 128 + k] : Wc[k];
}

// ---------------- K1: big GEMM, k-split 4 -> partials (unchanged) ----------------
__global__ __launch_bounds__(256, 4) void k_gemm(const float* __restrict__ inp,
                                                 const float* __restrict__ Wt,
                                                 float* __restrict__ Pf,
                                                 double* __restrict__ Pd) {
  __shared__ __align__(16) float xs[64 * 132];
  __shared__ double redd[2][64][2];
  int tid = threadIdx.x;
  int r = tid & 63;
  int w = __builtin_amdgcn_readfirstlane(tid >> 6);
  int rg = blockIdx.x >> 2, kq = blockIdx.x & 3;
  int rowbase = rg * 64;

  float acc[64];
  #pragma unroll
  for (int c = 0; c < 64; ++c) acc[c] = 0.f;
  double ad0 = 0.0, ad1 = 0.0;

  int s_rr[8], s_c4[8];
  #pragma unroll
  for (int i = 0; i < 8; ++i) {
    int idx = tid + i * 256;
    s_rr[i] = idx >> 5;
    s_c4[i] = idx & 31;
  }

  for (int kt = 0; kt < 8; ++kt) {
    int kb = kq * 1024 + kt * 128;
    #pragma unroll
    for (int i = 0; i < 8; ++i) {
      const float* g = inp + (size_t)(rowbase + s_rr[i]) * DIN + kb + s_c4[i] * 4;
      float4 v;
      v.x = g[0]; v.y = g[1]; v.z = g[2]; v.w = g[3];
      *(float4*)&xs[s_rr[i] * 132 + s_c4[i] * 4] = v;
    }
    __syncthreads();
    const float* wkbase = Wt + (size_t)(kb + w * 32) * 68;
    #pragma unroll
    for (int kk = 0; kk < 8; ++kk) {
      float4 xv = *(const float4*)&xs[r * 132 + w * 32 + kk * 4];
      #pragma unroll
      for (int j = 0; j < 4; ++j) {
        float x = (j == 0) ? xv.x : (j == 1) ? xv.y : (j == 2) ? xv.z : xv.w;
        const float* wp = wkbase + (size_t)(kk * 4 + j) * 68;
        #pragma unroll
        for (int c = 0; c < 64; ++c) acc[c] = fmaf(x, wp[c], acc[c]);
        double xd = (double)x;
        ad0 = fma(xd, (double)wp[64], ad0);
        ad1 = fma(xd, (double)wp[65], ad1);
      }
    }
    __syncthreads();
  }

  float* red = xs;
  if (w >= 2) {
    float* d = red + ((size_t)(w - 2) * 64 + r) * 65;
    #pragma unroll
    for (int c = 0; c < 64; ++c) d[c] = acc[c];
    redd[w - 2][r][0] = ad0; redd[w - 2][r][1] = ad1;
  }
  __syncthreads();
  if (w < 2) {
    const float* s = red + ((size_t)w * 64 + r) * 65;
    #pragma unroll
    for (int c = 0; c < 64; ++c) acc[c] += s[c];
    ad0 += redd[w][r][0]; ad1 += redd[w][r][1];
  }
  __syncthreads();
  if (w == 1) {
    float* d = red + (size_t)r * 65;
    #pragma unroll
    for (int c = 0; c < 64; ++c) d[c] = acc[c];
    redd[0][r][0] = ad0; redd[0][r][1] = ad1;
  }
  __syncthreads();
  if (w == 0) {
    const float* s = red + (size_t)r * 65;
    #pragma unroll
    for (int c = 0; c < 64; ++c) acc[c] += s[c];
    ad0 += redd[0][r][0]; ad1 += redd[0][r][1];
    int row = rowbase + r;
    float* po = Pf + (size_t)kq * NROWS * 64 + (size_t)row * 64;
    #pragma unroll
    for (int c = 0; c < 64; ++c) po[c] = acc[c];
    Pd[(size_t)kq * NROWS * 2 + (size_t)row * 2 + 0] = ad0;
    Pd[(size_t)kq * NROWS * 2 + (size_t)row * 2 + 1] = ad1;
  }
}

// ---------------- K1b: reduce the 4 k-quarter partials (unchanged) ----------------
__global__ void k_reduce(const float* __restrict__ Pf, const double* __restrict__ Pd,
                         float* __restrict__ Xf, double* __restrict__ Xb) {
  size_t gid = (size_t)blockIdx.x * 256 + threadIdx.x;
  const size_t NF = (size_t)NROWS * 64;
  if (gid < NF) {
    Xf[gid] = (Pf[gid] + Pf[NF + gid]) + (Pf[2 * NF + gid] + Pf[3 * NF + gid]);
  } else if (gid < NF + (size_t)NROWS * 2) {
    size_t j = gid - NF;
    const size_t ND = (size_t)NROWS * 2;
    Xb[j] = (Pd[j] + Pd[ND + j]) + (Pd[2 * ND + j] + Pd[3 * ND + j]);
  }
}

// ---------------- K1c: GI_x[rn][i] = Wih_s . (Xf[rn]+bf)  (+ CX at col 192) ----------------
// 256 blocks x 256 thr; lane = row-in-block, wave = output chunk of 48(+1).
__global__ __launch_bounds__(256) void k_gemm2(const float* __restrict__ Xf,
                                               const float* __restrict__ bf,
                                               const float* __restrict__ Wt2,
                                               float* __restrict__ GIx) {
  int tid = threadIdx.x;
  int lane = tid & 63;
  int w = __builtin_amdgcn_readfirstlane(tid >> 6);
  int row = blockIdx.x * 64 + lane;
  int i0 = w * 48;

  float x[64];
  const float* xr = Xf + (size_t)row * 64;
  #pragma unroll
  for (int k4 = 0; k4 < 16; ++k4) {
    float4 xv = *(const float4*)&xr[k4 * 4];
    float4 bv = *(const float4*)&bf[k4 * 4];
    x[k4 * 4 + 0] = xv.x + bv.x;
    x[k4 * 4 + 1] = xv.y + bv.y;
    x[k4 * 4 + 2] = xv.z + bv.z;
    x[k4 * 4 + 3] = xv.w + bv.w;
  }
  float acc[48];
  #pragma unroll
  for (int j = 0; j < 48; ++j) acc[j] = 0.f;
  float acc48 = 0.f;
  for (int k = 0; k < 64; ++k) {
    const float* wp = Wt2 + (size_t)k * 208 + i0;   // wave-uniform -> scalar loads
    float xk = x[k];
    #pragma unroll
    for (int j = 0; j < 48; ++j) acc[j] = fmaf(xk, wp[j], acc[j]);
    if (w == 3) acc48 = fmaf(xk, wp[48], acc48);
  }
  float* o = GIx + (size_t)row * GIXST + i0;
  #pragma unroll
  for (int j = 0; j < 48; ++j) o[j] = acc[j];
  if (w == 3) o[48] = acc48;
}

// ---------------- K2: gumbel noise (JAX partitionable threefry), FP64 ----------------
// Re-gridded: 9 blocks per t (8 Gg chunks + 1 Gb) -> 1152 blocks.
__global__ void k_noise(double* __restrict__ Gg, double* __restrict__ Gb) {
  int b = blockIdx.x;
  int t = b / 9, c = b - t * 9;
  int tid = threadIdx.x;
  unsigned a, bk, k1a, k1b, k2a, k2b, o0, o1;
  tf2x32(0u, 42u, 0u, (unsigned)t, a, bk);     // keys[t]
  if (c < 8) {
    tf2x32(a, bk, 0u, 0u, k1a, k1b);
    int i0 = c * 1440;                         // 8*1440 = NB*NG
    for (int i = i0 + tid; i < i0 + 1440; i += 256) {
      tf2x32(k1a, k1b, 0u, (unsigned)i, o0, o1);
      Gg[(size_t)t * NB * NG + i] = bits_to_gumbel_d(o0 ^ o1);
    }
  } else {
    tf2x32(a, bk, 0u, 1u, k2a, k2b);
    tf2x32(k2a, k2b, 0u, (unsigned)tid, o0, o1);
    Gb[(size_t)t * NB * 2 + tid] = bits_to_gumbel_d(o0 ^ o1);
  }
}

// ---------------- K3: sequential scan — 4-phase, fully low-rank ----------------
// gi(t) = gih(h(t-1)) + GI_x[t] + GI_r + GI_g + b*m_b  (s eliminated).
// waves 1-3: gi assembly (P1), lg+argmax (P3), gih (P4). wave0: softmax/cg (P1),
// gates/h (P2), Wl/wc1 dots + stores (P3), combine+sampling (P4).
__global__ __launch_bounds__(256) void k_scan(
    const float* __restrict__ inp, const float* __restrict__ hx,
    const float* __restrict__ Wf,
    const float* __restrict__ Wih, const float* __restrict__ bih,
    const float* __restrict__ bhh, const float* __restrict__ Wc,
    const float* __restrict__ bc, const float* __restrict__ Wl,
    const float* __restrict__ bl, const float* __restrict__ Wpi,
    const float* __restrict__ bpi, const float* __restrict__ Wb,
    const float* __restrict__ bb,
    const float* __restrict__ GIx, const double* __restrict__ Xb,
    const double* __restrict__ Gg, const double* __restrict__ Gb,
    float* __restrict__ lgst, float* __restrict__ lbst,
    int* __restrict__ gidxst, int* __restrict__ bidxst,
    float* __restrict__ out) {
  const int n = blockIdx.x;
  const int tid = threadIdx.x;
  const int lane = tid & 63;
  const int w = __builtin_amdgcn_readfirstlane(tid >> 6);

  __shared__ __align__(16) float h_lds[64];
  __shared__ __align__(16) float gi_lds[192];
  __shared__ float pq_lds[4];        // Wl0.h, Wl1.h, Wl2.h, wc1.h
  __shared__ float cp_lds[2][8];     // [parity]: cg, pc0..4
  __shared__ float pm_lds[3][2];     // per-wave (m1, m2)
  __shared__ int   pidx_lds[3];
  __shared__ int   pub_i[4];         // t1, b1, c1 of prev step
  __shared__ float pub_f[2];         // b(prev) as float
  __shared__ int   nz_sh;
  __shared__ float ws_lds[29][64];   // Wf state cols (init only)
  __shared__ float rg0_lds[32];      // r0[14], g0[14], b0
  __shared__ int   ti_lds[16];       // tt[5], cnt[5], obj[5]

  const int i = tid - 64;                               // waves 1-3 thread id
  const int oi = (w >= 1) ? (w - 1) * 30 + lane : 0;    // lg output index

  // ---- waves 1..3 persistent state ----
  f32x2 wih_h[32];                   // Wih[i][64..127]
  f32x2 wpi_p[32];                   // Wpi[oi][0..63] (lane<30)
  float bihc = 0.f, bpi_r = 0.f;
  float Mg[14], V[5], WpiM[5];
  float m_b = 0.f, GI_r = 0.f, GI_g = 0.f, accR = 0.f, gihreg = 0.f;
  float gixA = 0.f;
  double gumA = 0.0, gumB = 0.0;
  #pragma unroll
  for (int j = 0; j < 14; ++j) Mg[j] = 0.f;
  #pragma unroll
  for (int k = 0; k < 5; ++k) { V[k] = 0.f; WpiM[k] = 0.f; }

  // ---- wave0 persistent state ----
  float rgbp = 0.f, hreg = 0.f;
  float mtr[5];
  float bhr_r = 0, bhz_r = 0, bhn_r = 0;
  float wc0 = 0, wc1 = 0, wl0 = 0, wl1 = 0, wl2 = 0;
  float bl0 = 0, bl1 = 0, bl2 = 0, bc0 = 0;
  float wbs0 = 0, wbs1 = 0;
  float kap[5], wg[14], wcB = 0.f;
  float cR = 0.f, cG = 0.f, CXa = 0.f;
  double S0 = 0.0, S1 = 0.0, bb0d = 0.0, bb1d = 0.0;
  double xb0 = 0.0, xb1 = 0.0, gb0 = 0.0, gb1 = 0.0;
  double xb0n = 0.0, xb1n = 0.0, gb0n = 0.0, gb1n = 0.0;
  int dsto = -1;
  int ttk[5], cnk[5], obk[5];
  float wfs[29];
  #pragma unroll
  for (int k = 0; k < 5; ++k) { mtr[k] = 0.f; kap[k] = 0.f; ttk[k] = 0; cnk[k] = 0; obk[k] = 0; }
  #pragma unroll
  for (int j = 0; j < 14; ++j) wg[j] = 0.f;
  #pragma unroll
  for (int k = 0; k < 29; ++k) wfs[k] = 0.f;

  if (tid == 0) nz_sh = 0;
  __syncthreads();
  {
    int any = 0;
    const float4* h4 = (const float4*)hx;
    for (int q = tid; q < (NB * STATE) / 4; q += 256) {
      float4 v = h4[q];
      any |= (v.x != 0.f) | (v.y != 0.f) | (v.z != 0.f) | (v.w != 0.f);
    }
    if (any) nz_sh = 1;
  }
  if (w == 0) {
    #pragma unroll
    for (int k = 0; k < 29; ++k) wfs[k] = Wf[(size_t)lane * WFCOLS + CONVOUT + k];
    bhr_r = bhh[lane]; bhz_r = bhh[64 + lane]; bhn_r = bhh[128 + lane];
    wc0 = Wc[lane]; wc1 = Wc[64 + lane]; bc0 = bc[0];
    wl0 = Wl[lane]; wl1 = Wl[64 + lane]; wl2 = Wl[128 + lane];
    bl0 = bl[0]; bl1 = bl[1]; bl2 = bl[2];
    bb0d = (double)bb[0]; bb1d = (double)bb[1];
    if (lane < 14) { wbs0 = Wb[CONVOUT + lane]; wbs1 = Wb[(size_t)WBCOLS + CONVOUT + lane]; }
    const float* r0 = inp + (size_t)n * DIN + CONVOUT;
    #pragma unroll
    for (int k = 0; k < 5; ++k) {
      int ttv = (int)r0[k], cntv = (int)r0[5 + k] - 1, objv = (int)r0[10 + k];
      ttk[k] = ttv; cnk[k] = cntv; obk[k] = objv;
      float v = 0.f;
      if (lane < 5)       v = (lane == ttv) ? 1.f : 0.f;
      else if (lane < 8)  v = ((lane - 5) == cntv) ? 1.f : 0.f;
      else if (lane < 14) v = ((lane - 8) == objv) ? 1.f : 0.f;
      mtr[k] = v;
      if (lane == 0) { ti_lds[k] = ttv; ti_lds[5 + k] = cntv; ti_lds[10 + k] = objv; }
    }
    // packed state layout: lanes 0-13 r, 14-27 g, 28 b, 29-33 p
    int src = -1;
    if (lane < 14)       { dsto = 5 + lane;          src = dsto; }
    else if (lane < 28)  { dsto = 83 + (lane - 14);  src = dsto; }
    else if (lane == 28) { dsto = 97;                src = 97; }
    else if (lane < 34)  { dsto = lane - 29;         src = dsto; }
    rgbp = (src >= 0) ? hx[(size_t)n * STATE + src] : 0.f;
    hreg = hx[(size_t)n * STATE + 19 + lane];
  }
  __syncthreads();   // nz_sh ready

  if (w == 0) {
    if (nz_sh == 0) {   // new episode: p[0]=1, r=g=M[:,0]
      if (lane == 29) rgbp = 1.f;
      else if (lane < 14) rgbp = mtr[0];
      else if (lane >= 14 && lane < 28) {
        int j = lane - 14;
        rgbp = (j < 5) ? ((j == ttk[0]) ? 1.f : 0.f)
             : (j < 8) ? (((j - 5) == cnk[0]) ? 1.f : 0.f)
                       : (((j - 8) == obk[0]) ? 1.f : 0.f);
      }
    }
    // publish init data
    #pragma unroll
    for (int j = 0; j < 29; ++j) ws_lds[j][lane] = wfs[j];
    if (lane < 28) rg0_lds[lane] = rgbp;           // r0[0..13], g0 at [14..27]
    if (lane == 28) { rg0_lds[28] = rgbp; pub_f[0] = rgbp; }
    h_lds[lane] = hreg;
    if (lane < 6) cp_lds[1][lane] = 0.f;           // parity-1 zeros -> t=0 GI update is identity
    if (lane < 3) pub_i[lane] = 0;
  }
  __syncthreads();   // published

  if (w == 0) {
    // one-time scalars: kap, wg, wcB
    #pragma unroll
    for (int k = 0; k < 5; ++k) {
      float wfrm = SEL5(wfs[0], wfs[1], wfs[2], wfs[3], wfs[4], ttk[k])
                 + SEL3(wfs[5], wfs[6], wfs[7], cnk[k])
                 + SEL6(wfs[8], wfs[9], wfs[10], wfs[11], wfs[12], wfs[13], obk[k]);
      kap[k] = dpp_sum_bcast(wc0 * wfrm);
    }
    #pragma unroll
    for (int j = 0; j < 14; ++j) wg[j] = dpp_sum_bcast(wc0 * wfs[14 + j]);
    wcB = dpp_sum_bcast(wc0 * wfs[28]);
    // cR/cG init from r0/g0 (per-lane products of wc0 with Wf.state columns, reduced)
    {
      float rs = 0.f, gs = 0.f;
      #pragma unroll
      for (int j = 0; j < 14; ++j) {
        rs = fmaf(wfs[j], rlane(rgbp, j), rs);
        gs = fmaf(wfs[14 + j], rlane(rgbp, 14 + j), gs);
      }
      cR = dpp_sum_bcast(wc0 * rs);
      cG = dpp_sum_bcast(wc0 * gs);
    }
    // S init (fp64)
    #pragma unroll
    for (int j = 0; j < 14; ++j) {
      double gv = (double)rlane(rgbp, 14 + j);
      S0 += gv * (double)rlane(wbs0, j);
      S1 += gv * (double)rlane(wbs1, j);
    }
    // t=0 prefetches
    CXa = GIx[((size_t)0 * NB + n) * GIXST + 192];
    xb0 = Xb[(size_t)n * 2 + 0]; xb1 = Xb[(size_t)n * 2 + 1];
    gb0 = Gb[(size_t)n * 2 + 0]; gb1 = Gb[(size_t)n * 2 + 1];
    // pq(0): Wl/wc1 dots on h(0)
    float p0 = wl0 * hreg, p1 = wl1 * hreg, p2 = wl2 * hreg, cah = wc1 * hreg;
    dpp_sum4(p0, p1, p2, cah);
    if (lane == 63) { pq_lds[0] = p0; pq_lds[1] = p1; pq_lds[2] = p2; pq_lds[3] = cah; }
  } else {
    // ---- waves: build M_r, M_g, m_b from Wih_s and published Wf columns ----
    float wsrow[64];
    {
      const f32x2* wr0 = (const f32x2*)&Wih[(size_t)i * 128];
      #pragma unroll
      for (int l2 = 0; l2 < 32; ++l2) { f32x2 v = wr0[l2]; wsrow[2*l2] = v.x; wsrow[2*l2+1] = v.y; }
    }
    float Mr[14];
    #pragma unroll
    for (int j = 0; j < 14; ++j) Mr[j] = 0.f;
    #pragma unroll
    for (int l = 0; l < 64; ++l) {
      float wv = wsrow[l];
      #pragma unroll
      for (int j = 0; j < 14; ++j) {
        Mr[j] = fmaf(wv, ws_lds[j][l], Mr[j]);
        Mg[j] = fmaf(wv, ws_lds[14 + j][l], Mg[j]);
      }
      m_b = fmaf(wv, ws_lds[28][l], m_b);
    }
    #pragma unroll
    for (int k = 0; k < 5; ++k) {
      int tt = ti_lds[k], cn = ti_lds[5 + k], ob = ti_lds[10 + k];
      V[k] = SEL5(Mr[0], Mr[1], Mr[2], Mr[3], Mr[4], tt)
           + SEL3(Mr[5], Mr[6], Mr[7], cn)
           + SEL6(Mr[8], Mr[9], Mr[10], Mr[11], Mr[12], Mr[13], ob);
    }
    GI_r = 0.f; GI_g = 0.f;
    #pragma unroll
    for (int j = 0; j < 14; ++j) {
      GI_r = fmaf(Mr[j], rg0_lds[j], GI_r);
      GI_g = fmaf(Mg[j], rg0_lds[14 + j], GI_g);
    }
    // persistent weight rows
    {
      const f32x2* wr = (const f32x2*)&Wih[(size_t)i * 128 + 64];
      #pragma unroll
      for (int k2 = 0; k2 < 32; ++k2) wih_h[k2] = wr[k2];
      bihc = bih[i];
    }
    if (lane < 30) {
      const f32x2* pr = (const f32x2*)&Wpi[(size_t)oi * 78];
      #pragma unroll
      for (int k2 = 0; k2 < 32; ++k2) wpi_p[k2] = pr[k2];
      bpi_r = bpi[oi];
      const float* wp = Wpi + (size_t)oi * 78 + 64;
      #pragma unroll
      for (int k = 0; k < 5; ++k)
        WpiM[k] = wp[ti_lds[k]] + wp[5 + ti_lds[5 + k]] + wp[8 + ti_lds[10 + k]];
      accR = 0.f;
      #pragma unroll
      for (int j = 0; j < 14; ++j) accR = fmaf(wp[j], rg0_lds[j], accR);
      gumA = Gg[(size_t)n * NG + oi];
    }
    gixA = GIx[((size_t)0 * NB + n) * GIXST + i];
    // gih(0) from h(0)
    {
      const f32x2* hp = (const f32x2*)h_lds;
      f32x2 A = {bihc, 0.f}, B = {0.f, 0.f};
      #pragma unroll
      for (int k2 = 0; k2 < 32; k2 += 2) {
        f32x2 h0 = hp[k2], h1 = hp[k2 + 1];
        A.x = fmaf(wih_h[k2].x, h0.x, A.x);
        A.y = fmaf(wih_h[k2].y, h0.y, A.y);
        B.x = fmaf(wih_h[k2 + 1].x, h1.x, B.x);
        B.y = fmaf(wih_h[k2 + 1].y, h1.y, B.y);
      }
      gihreg = (A.x + A.y) + (B.x + B.y);
    }
  }
  __syncthreads();

  const size_t outF = (size_t)T_STEPS * NB * STATE;

  float cg = 0.f;
  double cgd = 0.0;

  #pragma unroll 1
  for (int t = 0; t < T_STEPS; ++t) {
    // ======== P1: wave0 softmax/cg/p/r  ||  waves assemble gi(t) ========
    if (w == 0) {
      float P0 = pq_lds[0] + bl0, P1v = pq_lds[1] + bl1, P2v = pq_lds[2] + bl2;
      float cgaH = pq_lds[3];
      float mx = fmaxf(P0, fmaxf(P1v, P2v));
      float e0 = expf(P0 - mx), e1 = expf(P1v - mx), e2 = expf(P2v - mx);
      float se = e0 + e1 + e2;
      float l0 = e0 / se, l1 = e1 / se, l2 = e2 / se;
      float bprev = rlane(rgbp, 28);
      float cga = CXa + cR + cG + bprev * wcB + cgaH;
      cg = 1.f / (1.f + expf(-(cga + bc0)));
      cgd = (double)cg;
      float pv0 = rlane(rgbp, 29), pv1 = rlane(rgbp, 30), pv2 = rlane(rgbp, 31);
      float pv3 = rlane(rgbp, 32), pv4 = rlane(rgbp, 33);
      float pc0 = pv0 * l1 + pv1 * l2;
      float pc1 = pv0 * l0 + pv1 * l1 + pv2 * l2;
      float pc2 = pv1 * l0 + pv2 * l1 + pv3 * l2;
      float pc3 = pv2 * l0 + pv3 * l1 + pv4 * l2;
      float pc4 = pv3 * l0 + pv4 * l1;
      if (lane >= 29 && lane < 34) {
        float pcl = (lane == 29) ? pc0 : (lane == 30) ? pc1 : (lane == 31) ? pc2
                  : (lane == 32) ? pc3 : pc4;
        rgbp = cg * pcl + (1.f - cg) * rgbp;
      }
      if (lane < 14) {
        float rn2 = pc0 * mtr[0] + pc1 * mtr[1] + pc2 * mtr[2] + pc3 * mtr[3] + pc4 * mtr[4];
        rgbp = cg * rn2 + (1.f - cg) * rgbp;
      }
      cR = cg * (pc0 * kap[0] + pc1 * kap[1] + pc2 * kap[2] + pc3 * kap[3] + pc4 * kap[4])
         + (1.f - cg) * cR;
      if (lane == 0) {
        float* cp = cp_lds[t & 1];
        cp[0] = cg; cp[1] = pc0; cp[2] = pc1; cp[3] = pc2; cp[4] = pc3; cp[5] = pc4;
      }
    } else {
      const float* cp = cp_lds[(t + 1) & 1];
      float cgp = cp[0];
      float rmix = cp[1] * V[0] + cp[2] * V[1] + cp[3] * V[2] + cp[4] * V[3] + cp[5] * V[4];
      GI_r = cgp * rmix + (1.f - cgp) * GI_r;
      int pt1 = pub_i[0], pb1 = pub_i[1], pc1i = pub_i[2];
      float mgs = SEL5(Mg[0], Mg[1], Mg[2], Mg[3], Mg[4], pt1)
                + SEL3(Mg[5], Mg[6], Mg[7], pb1)
                + SEL6(Mg[8], Mg[9], Mg[10], Mg[11], Mg[12], Mg[13], pc1i);
      GI_g = cgp * mgs + (1.f - cgp) * GI_g;
      float bprev = pub_f[0];
      gi_lds[i] = gihreg + gixA + GI_r + GI_g + bprev * m_b;
    }
    bar_lds();   // ---- bar1: gi(t) ready ----

    // ======== P2: wave0 gates/h  ||  waves prefetch t+1 ========
    if (w == 0) {
      float g0 = gi_lds[lane], g1 = gi_lds[64 + lane], g2 = gi_lds[128 + lane];
      float rg = 1.f / (1.f + expf(-(g0 + bhr_r)));
      float z  = 1.f / (1.f + expf(-(g1 + bhz_r)));
      float nn = tanhf(g2 + rg * bhn_r);
      hreg = cg * ((1.f - z) * nn) + (1.f - cg) * hreg;
      h_lds[lane] = hreg;
    } else {
      int tn = (t + 1 < T_STEPS) ? t + 1 : t;
      gixA = GIx[((size_t)tn * NB + n) * GIXST + i];
      if (lane < 30) gumB = Gg[(size_t)tn * NB * NG + (size_t)n * NG + oi];
    }
    bar_lds();   // ---- bar2: h(t) ready ----

    // ======== P3: waves lg+argmax  ||  wave0 dots(t+1) + stores + prefetch ========
    if (w != 0) {
      const float* cp = cp_lds[t & 1];
      float cgc = cp[0];
      float vb = NEGINFF;
      if (lane < 30) {
        float rmx = cp[1] * WpiM[0] + cp[2] * WpiM[1] + cp[3] * WpiM[2]
                  + cp[4] * WpiM[3] + cp[5] * WpiM[4];
        accR = cgc * rmx + (1.f - cgc) * accR;
        const f32x2* hp = (const f32x2*)h_lds;
        f32x2 A = {bpi_r + accR, 0.f}, B = {0.f, 0.f};
        #pragma unroll
        for (int k2 = 0; k2 < 32; k2 += 2) {
          f32x2 h0 = hp[k2], h1 = hp[k2 + 1];
          A.x = fmaf(wpi_p[k2].x, h0.x, A.x);
          A.y = fmaf(wpi_p[k2].y, h0.y, A.y);
          B.x = fmaf(wpi_p[k2 + 1].x, h1.x, B.x);
          B.y = fmaf(wpi_p[k2 + 1].y, h1.y, B.y);
        }
        float lgv = (A.x + A.y) + (B.x + B.y);
        lgst[((size_t)t * NB + n) * NG + oi] = lgv;
        vb = (float)(gumA + (double)lgv);
      }
      gumA = gumB;
      float m1 = vb, m2 = NEGINFF;
      dpp_amax2(m1, m2);
      float M1w = rlane(m1, 63);
      unsigned long long bm = __ballot(vb == M1w);
      int il = __ffsll(bm) - 1;
      if (lane == 63) { pm_lds[w - 1][0] = m1; pm_lds[w - 1][1] = m2; pidx_lds[w - 1] = il; }
    } else {
      float p0 = wl0 * hreg, p1 = wl1 * hreg, p2 = wl2 * hreg, cah = wc1 * hreg;
      dpp_sum4(p0, p1, p2, cah);
      if (lane == 63) { pq_lds[0] = p0; pq_lds[1] = p1; pq_lds[2] = p2; pq_lds[3] = cah; }
      size_t rn = (size_t)t * NB + n;
      float* ob = out + rn * STATE;
      ob[19 + lane] = hreg;
      if (dsto >= 0 && (lane < 14 || lane >= 29)) ob[dsto] = rgbp;   // r, p
      int tn = (t + 1 < T_STEPS) ? t + 1 : t;
      CXa = GIx[((size_t)tn * NB + n) * GIXST + 192];
      xb0n = Xb[((size_t)tn * NB + n) * 2 + 0];
      xb1n = Xb[((size_t)tn * NB + n) * 2 + 1];
      gb0n = Gb[((size_t)tn * NB + n) * 2 + 0];
      gb1n = Gb[((size_t)tn * NB + n) * 2 + 1];
    }
    bar_lds();   // ---- bar3: argmax partials ready ----

    // ======== P4: wave0 combine+sampling  ||  waves gih(t+1) ========
    if (w == 0) {
      float m1a = pm_lds[0][0], m2a = pm_lds[0][1];
      float m1b = pm_lds[1][0], m2b = pm_lds[1][1];
      float m1c = pm_lds[2][0], m2c = pm_lds[2][1];
      float M1 = fmaxf(m1a, fmaxf(m1b, m1c));
      float M2; int gidx;
      if (m1a == M1)      { M2 = fmaxf(m2a, fmaxf(m1b, m1c)); gidx = pidx_lds[0]; }
      else if (m1b == M1) { M2 = fmaxf(m2b, fmaxf(m1a, m1c)); gidx = 30 + pidx_lds[1]; }
      else                { M2 = fmaxf(m2c, fmaxf(m1a, m1b)); gidx = 60 + pidx_lds[2]; }
      if (M1 - M2 < 3e-5f) {
        // rare fp64 slow path: exact recompute from global weights
        double gum0s = Gg[(size_t)t * NB * NG + (size_t)n * NG + lane];
        double gum1s = (lane < 26) ? Gg[(size_t)t * NB * NG + (size_t)n * NG + 64 + lane] : 0.0;
        double e0d = (double)bpi[lane];
        double e1d = (lane < 26) ? (double)bpi[64 + lane] : -1.0e300;
        #pragma unroll 1
        for (int k = 0; k < 64; ++k) {
          double hv2 = (double)rlane(hreg, k);
          e0d = fma((double)Wpi[(size_t)lane * 78 + k], hv2, e0d);
          if (lane < 26) e1d = fma((double)Wpi[(size_t)(64 + lane) * 78 + k], hv2, e1d);
        }
        #pragma unroll 1
        for (int k = 0; k < 14; ++k) {
          double rv = (double)rlane(rgbp, k);
          e0d = fma((double)Wpi[(size_t)lane * 78 + 64 + k], rv, e0d);
          if (lane < 26) e1d = fma((double)Wpi[(size_t)(64 + lane) * 78 + 64 + k], rv, e1d);
        }
        double kk0 = e0d + gum0s;
        double kk1 = (lane < 26) ? e1d + gum1s : -1.0e300;
        double d1; int di;
        if (kk1 > kk0) { d1 = kk1; di = lane + 64; } else { d1 = kk0; di = lane; }
        #pragma unroll
        for (int off = 32; off; off >>= 1) {
          double od = __shfl_xor(d1, off, 64);
          int    oid = __shfl_xor(di, off, 64);
          if (od > d1 || (od == d1 && oid < di)) { d1 = od; di = oid; }
        }
        gidx = di;
      }
      int t1 = gidx / 18, rem = gidx - t1 * 18;
      int b1 = rem / 6, c1 = rem - b1 * 6;
      if (lane >= 14 && lane < 28) {
        int j = lane - 14;
        float ge = (j < 5) ? ((j == t1) ? 1.f : 0.f)
                 : (j < 8) ? (((j - 5) == b1) ? 1.f : 0.f)
                           : (((j - 8) == c1) ? 1.f : 0.f);
        rgbp = cg * ge + (1.f - cg) * rgbp;
      }
      float wgs = SEL5(wg[0], wg[1], wg[2], wg[3], wg[4], t1)
                + SEL3(wg[5], wg[6], wg[7], b1)
                + SEL6(wg[8], wg[9], wg[10], wg[11], wg[12], wg[13], c1);
      cG = cg * wgs + (1.f - cg) * cG;
      double u0 = (double)rlane(wbs0, t1) + (double)rlane(wbs0, 5 + b1) + (double)rlane(wbs0, 8 + c1);
      double u1 = (double)rlane(wbs1, t1) + (double)rlane(wbs1, 5 + b1) + (double)rlane(wbs1, 8 + c1);
      S0 = cgd * u0 + (1.0 - cgd) * S0;
      S1 = cgd * u1 + (1.0 - cgd) * S1;
      double lb0 = xb0 + bb0d + S0;
      double lb1 = xb1 + bb1d + S1;
      int bi = ((lb1 + gb1) > (lb0 + gb0)) ? 1 : 0;
      if (lane == 28) rgbp = (float)bi;
      size_t rn = (size_t)t * NB + n;
      float* ob = out + rn * STATE;
      if (dsto >= 0 && lane >= 14 && lane < 29) ob[dsto] = rgbp;     // g, b
      if (lane == 0) {
        lbst[rn * 2 + 0] = (float)lb0; lbst[rn * 2 + 1] = (float)lb1;
        gidxst[rn] = gidx; bidxst[rn] = bi;
        pub_i[0] = t1; pub_i[1] = b1; pub_i[2] = c1;
      }
      if (lane == 28) pub_f[0] = rgbp;
      if (t == T_STEPS - 1) {
        float* of = out + outF + (size_t)n * STATE;
        if (dsto >= 0) of[dsto] = rgbp;
        of[19 + lane] = hreg;
      }
      xb0 = xb0n; xb1 = xb1n; gb0 = gb0n; gb1 = gb1n;
    } else {
      // gih(t+1) from h(t)
      const f32x2* hp = (const f32x2*)h_lds;
      f32x2 A = {bihc, 0.f}, B = {0.f, 0.f};
      #pragma unroll
      for (int k2 = 0; k2 < 32; k2 += 2) {
        f32x2 h0 = hp[k2], h1 = hp[k2 + 1];
        A.x = fmaf(wih_h[k2].x, h0.x, A.x);
        A.y = fmaf(wih_h[k2].y, h0.y, A.y);
        B.x = fmaf(wih_h[k2 + 1].x, h1.x, B.x);
        B.y = fmaf(wih_h[k2 + 1].y, h1.y, B.y);
      }
      gihreg = (A.x + A.y) + (B.x + B.y);
    }
    bar_lds();   // ---- bar_s: state(t) published ----
  }
}

// ---------------- K4: deferred log-prob (fp32, fully parallel, unchanged) ----------------
__global__ __launch_bounds__(256) void k_lp(const float* __restrict__ lgst,
                                            const float* __restrict__ lbst,
                                            const int* __restrict__ gidxst,
                                            const int* __restrict__ bidxst,
                                            float* __restrict__ out) {
  int tid = threadIdx.x, lane = tid & 63, w = tid >> 6;
  size_t rn = (size_t)blockIdx.x * 4 + w;   // < 16384
  const float* lg = lgst + rn * NG;
  float v0 = lg[lane];
  float v1 = (lane < 26) ? lg[64 + lane] : -3.0e38f;
  float ml = fmaxf(v0, v1);
  #pragma unroll
  for (int off = 32; off; off >>= 1) ml = fmaxf(ml, __shfl_xor(ml, off, 64));
  float e = expf(v0 - ml) + ((lane < 26) ? expf(v1 - ml) : 0.f);
  #pragma unroll
  for (int off = 32; off; off >>= 1) e += __shfl_xor(e, off, 64);
  int gi = gidxst[rn];
  float lpg = (lg[gi] - ml) - logf(e);
  float lb0 = lbst[rn * 2 + 0], lb1 = lbst[rn * 2 + 1];
  int bi = bidxst[rn];
  float mx = fmaxf(lb0, lb1);
  float seb = expf(lb0 - mx) + expf(lb1 - mx);
  float lpb = ((bi ? lb1 : lb0) - mx) - logf(seb);
  if (lane == 0) {
    int t = (int)(rn / NB), n = (int)(rn % NB);
    float lp = lpg + lpb;
    out[rn * STATE + 98] = lp;
    if (t == T_STEPS - 1) out[(size_t)T_STEPS * NB * STATE + (size_t)n * STATE + 98] = lp;
  }
}

// ---------------- launcher ----------------
extern "C" void kernel_launch(void* const* d_in, const int* in_sizes, int n_in,
                              void* d_out, int out_size, void* d_ws, size_t ws_size,
                              hipStream_t stream) {
  const float* inp = (const float*)d_in[0];
  const float* hx  = (const float*)d_in[1];
  const float* Wf  = (const float*)d_in[2];
  const float* bf  = (const float*)d_in[3];
  const float* Wih = (const float*)d_in[4];
  const float* bih = (const float*)d_in[5];
  const float* bhh = (const float*)d_in[6];
  const float* Wc  = (const float*)d_in[7];
  const float* bc  = (const float*)d_in[8];
  const float* Wl  = (const float*)d_in[9];
  const float* bl  = (const float*)d_in[10];
  const float* Wpi = (const float*)d_in[11];
  const float* bpi = (const float*)d_in[12];
  const float* Wb  = (const float*)d_in[13];
  const float* bb  = (const float*)d_in[14];
  float* out = (float*)d_out;

  // ws layout (~35.5 MB, same footprint; dead regions re-aliased):
  double* Gg  = (double*)d_ws;                        // 128*128*90 d
  double* Gb  = Gg + (size_t)T_STEPS * NB * NG;       // 128*128*2 d
  double* Xb  = Gb + (size_t)T_STEPS * NB * 2;        // 16384*2 d
  double* Pd  = Xb + (size_t)NROWS * 2;               // 4*16384*2 d   (dead after k_reduce)
  float*  Wt  = (float*)(Pd + (size_t)4 * NROWS * 2); // 4096*68 f     (dead after k_gemm)
  float*  Wt2 = Wt + (size_t)4096 * 68;               // 64*208 f      (dead after k_gemm2)
  float*  Xf  = Wt2 + (size_t)64 * 208;               // 16384*64 f    (dead after k_gemm2)
  float*  Pf  = Xf + (size_t)NROWS * 64;              // 4*16384*64 f  (dead after k_reduce)
  // GI_x aliases Pf (written by k_gemm2 after k_reduce consumed Pf):
  float*  GIx = Pf;                                   // 16384*193 f <= Pf size
  // lgst group aliases Pd+Wt+Wt2+Xf (all dead before k_scan writes):
  float*  lgst = (float*)Pd;                          // 16384*90 f
  float*  lbst = lgst + (size_t)NROWS * NG;           // 16384*2 f
  int*    gidxst = (int*)(lbst + (size_t)NROWS * 2);  // 16384
  int*    bidxst = gidxst + NROWS;                    // 16384

  k_transpose<<<(66 * 4096) / 256, 256, 0, stream>>>(Wf, Wb, Wt);
  k_tr2<<<(64 * GIXST + 255) / 256, 256, 0, stream>>>(Wih, Wc, Wt2);
  k_gemm<<<1024, 256, 0, stream>>>(inp, Wt, Pf, Pd);
  {
    size_t tot = (size_t)NROWS * 64 + (size_t)NROWS * 2;
    k_reduce<<<(int)((tot + 255) / 256), 256, 0, stream>>>(Pf, Pd, Xf, Xb);
  }
  k_gemm2<<<256, 256, 0, stream>>>(Xf, bf, Wt2, GIx);
  k_noise<<<T_STEPS * 9, 256, 0, stream>>>(Gg, Gb);
  k_scan<<<NB, 256, 0, stream>>>(inp, hx, Wf, Wih, bih, bhh, Wc, bc, Wl, bl,
                                 Wpi, bpi, Wb, bb, GIx, Xb, Gg, Gb,
                                 lgst, lbst, gidxst, bidxst, out);
  k_lp<<<NROWS / 4, 256, 0, stream>>>(lgst, lbst, gidxst, bidxst, out);
}

// Round 5
// 940.618 us; speedup vs baseline: 1.0045x; 1.0045x over previous
//
#include <hip/hip_runtime.h>
#include <stdint.h>
#include <math.h>

// Problem constants (from reference)
#define T_STEPS 128
#define NB      128
#define HID     64
#define CONVOUT 4096
#define NSUB    5
#define SUBSZ   14      // A+B+C = 5+3+6
#define NG      90      // A*B*C
#define STATE   99
#define DIN     4111    // CONVOUT + 3*NSUB
#define WFCOLS  4125    // CONVOUT + 2*SUBSZ + 1
#define WBCOLS  4110    // CONVOUT + SUBSZ
#define NROWS   (T_STEPS * NB)   // 16384
#define GIXST   193              // GI_x row stride (192 gi cols + CX)

#define NEGINFF (-3.0e38f)

typedef __attribute__((ext_vector_type(2))) float f32x2;

#define SEL5(a,b,c,d,e,ix) ((ix)==0?(a):(ix)==1?(b):(ix)==2?(c):(ix)==3?(d):(e))
#define SEL3(a,b,c,ix)     ((ix)==0?(a):(ix)==1?(b):(c))
#define SEL6(a,b,c,d,e,f,ix) ((ix)==0?(a):(ix)==1?(b):(ix)==2?(c):(ix)==3?(d):(ix)==4?(e):(f))

// ---------------- Threefry-2x32 (JAX-compatible) ----------------
__device__ __forceinline__ void tf2x32(unsigned k0, unsigned k1,
                                       unsigned x0, unsigned x1,
                                       unsigned &o0, unsigned &o1) {
  unsigned K0 = k0, K1 = k1, K2 = k0 ^ k1 ^ 0x1BD11BDAu;
  x0 += K0; x1 += K1;
  const int R0[4] = {13, 15, 26, 6};
  const int R1[4] = {17, 29, 16, 24};
  #pragma unroll
  for (int j = 0; j < 4; ++j) { x0 += x1; x1 = (x1 << R0[j]) | (x1 >> (32 - R0[j])); x1 ^= x0; }
  x0 += K1; x1 += K2 + 1u;
  #pragma unroll
  for (int j = 0; j < 4; ++j) { x0 += x1; x1 = (x1 << R1[j]) | (x1 >> (32 - R1[j])); x1 ^= x0; }
  x0 += K2; x1 += K0 + 2u;
  #pragma unroll
  for (int j = 0; j < 4; ++j) { x0 += x1; x1 = (x1 << R0[j]) | (x1 >> (32 - R0[j])); x1 ^= x0; }
  x0 += K0; x1 += K1 + 3u;
  #pragma unroll
  for (int j = 0; j < 4; ++j) { x0 += x1; x1 = (x1 << R1[j]) | (x1 >> (32 - R1[j])); x1 ^= x0; }
  x0 += K1; x1 += K2 + 4u;
  #pragma unroll
  for (int j = 0; j < 4; ++j) { x0 += x1; x1 = (x1 << R0[j]) | (x1 >> (32 - R0[j])); x1 ^= x0; }
  x0 += K2; x1 += K0 + 5u;
  o0 = x0; o1 = x1;
}

__device__ __forceinline__ double bits_to_gumbel_d(unsigned bits) {
  float f = __uint_as_float((bits >> 9) | 0x3f800000u) - 1.0f;   // exact in f32
  const double tiny = (double)1.17549435e-38f;
  double u = fmax(tiny, (double)f + tiny);
  return -log(-log(u));
}

__device__ __forceinline__ float rlane(float v, int l) {
  return __int_as_float(__builtin_amdgcn_readlane(__float_as_int(v), l));
}

// DPP shifted copy: lanes without a source (or rows masked off) get `fill`.
template<int CTRL, int RM>
__device__ __forceinline__ float dpp_mv(float x, float fill) {
  return __int_as_float(__builtin_amdgcn_update_dpp(
      __float_as_int(fill), __float_as_int(x), CTRL, RM, 0xF, false));
}

// 4-way sum reduce (valid at lane 63)
__device__ __forceinline__ void dpp_sum4(float &a, float &b, float &c, float &d) {
  #define S4(C, RM) { a += dpp_mv<C,RM>(a,0.f); b += dpp_mv<C,RM>(b,0.f); \
                      c += dpp_mv<C,RM>(c,0.f); d += dpp_mv<C,RM>(d,0.f); }
  S4(0x111,0xF) S4(0x112,0xF) S4(0x114,0xF) S4(0x118,0xF) S4(0x142,0xA) S4(0x143,0xC)
  #undef S4
}

// (max, runner-up) pair reduce (valid at lane 63)
__device__ __forceinline__ void dpp_amax2(float &m1, float &m2) {
  #define A2(C, RM) { float o1 = dpp_mv<C,RM>(m1,NEGINFF), o2 = dpp_mv<C,RM>(m2,NEGINFF); \
    m2 = fmaxf(fmaxf(m2,o2), fminf(m1,o1)); m1 = fmaxf(m1,o1); }
  A2(0x111,0xF) A2(0x112,0xF) A2(0x114,0xF) A2(0x118,0xF) A2(0x142,0xA) A2(0x143,0xC)
  #undef A2
}

// single sum reduce, broadcast result to all lanes
__device__ __forceinline__ float dpp_sum_bcast(float v) {
  v += dpp_mv<0x111,0xF>(v, 0.f);
  v += dpp_mv<0x112,0xF>(v, 0.f);
  v += dpp_mv<0x114,0xF>(v, 0.f);
  v += dpp_mv<0x118,0xF>(v, 0.f);
  v += dpp_mv<0x142,0xA>(v, 0.f);
  v += dpp_mv<0x143,0xC>(v, 0.f);
  return rlane(v, 63);
}

// Barrier that waits LDS only (lgkmcnt(0)) — does NOT drain vmcnt.
__device__ __forceinline__ void bar_lds() {
  __asm__ volatile("" ::: "memory");
  __builtin_amdgcn_s_waitcnt(0xC07F);
  __builtin_amdgcn_s_barrier();
  __asm__ volatile("" ::: "memory");
}

// ---------------- K0: pack/transpose weights ----------------
__global__ void k_transpose(const float* __restrict__ Wf, const float* __restrict__ Wb,
                            float* __restrict__ Wt) {
  int idx = blockIdx.x * 256 + threadIdx.x;     // < 66*4096
  int c = idx >> 12;                            // 0..65
  int k = idx & 4095;
  float v = (c < 64) ? Wf[(size_t)c * WFCOLS + k] : Wb[(size_t)(c - 64) * WBCOLS + k];
  Wt[(size_t)k * 68 + c] = v;
}

// ---------------- K0b: Wt2[k][i] = Wih[i][k] (i<192) / Wc[k] (i==192) ----------------
__global__ void k_tr2(const float* __restrict__ Wih, const float* __restrict__ Wc,
                      float* __restrict__ Wt2) {
  int idx = blockIdx.x * 256 + threadIdx.x;
  if (idx >= 64 * GIXST) return;
  int k = idx / GIXST, i = idx - k * GIXST;
  Wt2[(size_t)k * 208 + i] = (i < 192) ? Wih[(size_t)i * 128 + k] : Wc[k];
}

// ---------------- K1: big GEMM, k-split 4 -> partials (unchanged) ----------------
__global__ __launch_bounds__(256, 4) void k_gemm(const float* __restrict__ inp,
                                                 const float* __restrict__ Wt,
                                                 float* __restrict__ Pf,
                                                 double* __restrict__ Pd) {
  __shared__ __align__(16) float xs[64 * 132];
  __shared__ double redd[2][64][2];
  int tid = threadIdx.x;
  int r = tid & 63;
  int w = __builtin_amdgcn_readfirstlane(tid >> 6);
  int rg = blockIdx.x >> 2, kq = blockIdx.x & 3;
  int rowbase = rg * 64;

  float acc[64];
  #pragma unroll
  for (int c = 0; c < 64; ++c) acc[c] = 0.f;
  double ad0 = 0.0, ad1 = 0.0;

  int s_rr[8], s_c4[8];
  #pragma unroll
  for (int i = 0; i < 8; ++i) {
    int idx = tid + i * 256;
    s_rr[i] = idx >> 5;
    s_c4[i] = idx & 31;
  }

  for (int kt = 0; kt < 8; ++kt) {
    int kb = kq * 1024 + kt * 128;
    #pragma unroll
    for (int i = 0; i < 8; ++i) {
      const float* g = inp + (size_t)(rowbase + s_rr[i]) * DIN + kb + s_c4[i] * 4;
      float4 v;
      v.x = g[0]; v.y = g[1]; v.z = g[2]; v.w = g[3];
      *(float4*)&xs[s_rr[i] * 132 + s_c4[i] * 4] = v;
    }
    __syncthreads();
    const float* wkbase = Wt + (size_t)(kb + w * 32) * 68;
    #pragma unroll
    for (int kk = 0; kk < 8; ++kk) {
      float4 xv = *(const float4*)&xs[r * 132 + w * 32 + kk * 4];
      #pragma unroll
      for (int j = 0; j < 4; ++j) {
        float x = (j == 0) ? xv.x : (j == 1) ? xv.y : (j == 2) ? xv.z : xv.w;
        const float* wp = wkbase + (size_t)(kk * 4 + j) * 68;
        #pragma unroll
        for (int c = 0; c < 64; ++c) acc[c] = fmaf(x, wp[c], acc[c]);
        double xd = (double)x;
        ad0 = fma(xd, (double)wp[64], ad0);
        ad1 = fma(xd, (double)wp[65], ad1);
      }
    }
    __syncthreads();
  }

  float* red = xs;
  if (w >= 2) {
    float* d = red + ((size_t)(w - 2) * 64 + r) * 65;
    #pragma unroll
    for (int c = 0; c < 64; ++c) d[c] = acc[c];
    redd[w - 2][r][0] = ad0; redd[w - 2][r][1] = ad1;
  }
  __syncthreads();
  if (w < 2) {
    const float* s = red + ((size_t)w * 64 + r) * 65;
    #pragma unroll
    for (int c = 0; c < 64; ++c) acc[c] += s[c];
    ad0 += redd[w][r][0]; ad1 += redd[w][r][1];
  }
  __syncthreads();
  if (w == 1) {
    float* d = red + (size_t)r * 65;
    #pragma unroll
    for (int c = 0; c < 64; ++c) d[c] = acc[c];
    redd[0][r][0] = ad0; redd[0][r][1] = ad1;
  }
  __syncthreads();
  if (w == 0) {
    const float* s = red + (size_t)r * 65;
    #pragma unroll
    for (int c = 0; c < 64; ++c) acc[c] += s[c];
    ad0 += redd[0][r][0]; ad1 += redd[0][r][1];
    int row = rowbase + r;
    float* po = Pf + (size_t)kq * NROWS * 64 + (size_t)row * 64;
    #pragma unroll
    for (int c = 0; c < 64; ++c) po[c] = acc[c];
    Pd[(size_t)kq * NROWS * 2 + (size_t)row * 2 + 0] = ad0;
    Pd[(size_t)kq * NROWS * 2 + (size_t)row * 2 + 1] = ad1;
  }
}

// ---------------- K1b: reduce the 4 k-quarter partials (unchanged) ----------------
__global__ void k_reduce(const float* __restrict__ Pf, const double* __restrict__ Pd,
                         float* __restrict__ Xf, double* __restrict__ Xb) {
  size_t gid = (size_t)blockIdx.x * 256 + threadIdx.x;
  const size_t NF = (size_t)NROWS * 64;
  if (gid < NF) {
    Xf[gid] = (Pf[gid] + Pf[NF + gid]) + (Pf[2 * NF + gid] + Pf[3 * NF + gid]);
  } else if (gid < NF + (size_t)NROWS * 2) {
    size_t j = gid - NF;
    const size_t ND = (size_t)NROWS * 2;
    Xb[j] = (Pd[j] + Pd[ND + j]) + (Pd[2 * ND + j] + Pd[3 * ND + j]);
  }
}

// ---------------- K1c: GI_x[rn][i] = Wih_s . (Xf[rn]+bf)  (+ CX at col 192) ----------------
__global__ __launch_bounds__(256) void k_gemm2(const float* __restrict__ Xf,
                                               const float* __restrict__ bf,
                                               const float* __restrict__ Wt2,
                                               float* __restrict__ GIx) {
  int tid = threadIdx.x;
  int lane = tid & 63;
  int w = __builtin_amdgcn_readfirstlane(tid >> 6);
  int row = blockIdx.x * 64 + lane;
  int i0 = w * 48;

  float x[64];
  const float* xr = Xf + (size_t)row * 64;
  #pragma unroll
  for (int k4 = 0; k4 < 16; ++k4) {
    float4 xv = *(const float4*)&xr[k4 * 4];
    float4 bv = *(const float4*)&bf[k4 * 4];
    x[k4 * 4 + 0] = xv.x + bv.x;
    x[k4 * 4 + 1] = xv.y + bv.y;
    x[k4 * 4 + 2] = xv.z + bv.z;
    x[k4 * 4 + 3] = xv.w + bv.w;
  }
  float acc[48];
  #pragma unroll
  for (int j = 0; j < 48; ++j) acc[j] = 0.f;
  float acc48 = 0.f;
  for (int k = 0; k < 64; ++k) {
    const float* wp = Wt2 + (size_t)k * 208 + i0;   // wave-uniform -> scalar loads
    float xk = x[k];
    #pragma unroll
    for (int j = 0; j < 48; ++j) acc[j] = fmaf(xk, wp[j], acc[j]);
    if (w == 3) acc48 = fmaf(xk, wp[48], acc48);
  }
  float* o = GIx + (size_t)row * GIXST + i0;
  #pragma unroll
  for (int j = 0; j < 48; ++j) o[j] = acc[j];
  if (w == 3) o[48] = acc48;
}

// ---------------- K2: gumbel noise (JAX partitionable threefry), FP64 ----------------
// 9 blocks per t (8 Gg chunks + 1 Gb) -> 1152 blocks.
__global__ void k_noise(double* __restrict__ Gg, double* __restrict__ Gb) {
  int b = blockIdx.x;
  int t = b / 9, c = b - t * 9;
  int tid = threadIdx.x;
  unsigned a, bk, k1a, k1b, k2a, k2b, o0, o1;
  tf2x32(0u, 42u, 0u, (unsigned)t, a, bk);     // keys[t]
  if (c < 8) {
    tf2x32(a, bk, 0u, 0u, k1a, k1b);
    int i0 = c * 1440;                         // 8*1440 = NB*NG
    for (int i = i0 + tid; i < i0 + 1440; i += 256) {
      tf2x32(k1a, k1b, 0u, (unsigned)i, o0, o1);
      Gg[(size_t)t * NB * NG + i] = bits_to_gumbel_d(o0 ^ o1);
    }
  } else {
    tf2x32(a, bk, 0u, 1u, k2a, k2b);
    tf2x32(k2a, k2b, 0u, (unsigned)tid, o0, o1);
    Gb[(size_t)t * NB * 2 + tid] = bits_to_gumbel_d(o0 ^ o1);
  }
}

// ---------------- K3: sequential scan — 4-phase, fully low-rank ----------------
// gi(t) = gih(h(t-1)) + GI_x[t] + GI_r + GI_g + b*m_b  (s eliminated).
// __launch_bounds__(256, 1): 1 wave/SIMD -> full VGPR budget, NO SPILL (round-4
// regression was the compiler capping at 256 VGPR and spilling to scratch:
// WRITE_SIZE 14->111 MB).
__global__ __launch_bounds__(256, 1) void k_scan(
    const float* __restrict__ inp, const float* __restrict__ hx,
    const float* __restrict__ Wf,
    const float* __restrict__ Wih, const float* __restrict__ bih,
    const float* __restrict__ bhh, const float* __restrict__ Wc,
    const float* __restrict__ bc, const float* __restrict__ Wl,
    const float* __restrict__ bl, const float* __restrict__ Wpi,
    const float* __restrict__ bpi, const float* __restrict__ Wb,
    const float* __restrict__ bb,
    const float* __restrict__ GIx, const double* __restrict__ Xb,
    const double* __restrict__ Gg, const double* __restrict__ Gb,
    float* __restrict__ lgst, float* __restrict__ lbst,
    int* __restrict__ gidxst, int* __restrict__ bidxst,
    float* __restrict__ out) {
  const int n = blockIdx.x;
  const int tid = threadIdx.x;
  const int lane = tid & 63;
  const int w = __builtin_amdgcn_readfirstlane(tid >> 6);

  __shared__ __align__(16) float h_lds[64];
  __shared__ __align__(16) float gi_lds[192];
  __shared__ float pq_lds[4];        // Wl0.h, Wl1.h, Wl2.h, wc1.h
  __shared__ float cp_lds[2][8];     // [parity]: cg, pc0..4
  __shared__ float pm_lds[3][2];     // per-wave (m1, m2)
  __shared__ int   pidx_lds[3];
  __shared__ int   pub_i[4];         // t1, b1, c1 of prev step
  __shared__ float pub_f[2];         // b(prev) as float
  __shared__ int   nz_sh;
  __shared__ float ws_lds[29][64];   // Wf state cols (init only)
  __shared__ float rg0_lds[32];      // r0[14], g0[14], b0
  __shared__ int   ti_lds[16];       // tt[5], cnt[5], obj[5]

  const int i = tid - 64;                               // waves 1-3 thread id
  const int oi = (w >= 1) ? (w - 1) * 30 + lane : 0;    // lg output index

  // ---- waves 1..3 persistent state ----
  f32x2 wih_h[32];                   // Wih[i][64..127]
  f32x2 wpi_p[32];                   // Wpi[oi][0..63] (lane<30)
  float bihc = 0.f, bpi_r = 0.f;
  float Mg[14], V[5], WpiM[5];
  float m_b = 0.f, GI_r = 0.f, GI_g = 0.f, accR = 0.f, gihreg = 0.f;
  float gixA = 0.f;
  double gumA = 0.0, gumB = 0.0;
  #pragma unroll
  for (int j = 0; j < 14; ++j) Mg[j] = 0.f;
  #pragma unroll
  for (int k = 0; k < 5; ++k) { V[k] = 0.f; WpiM[k] = 0.f; }

  // ---- wave0 persistent state ----
  float rgbp = 0.f, hreg = 0.f;
  float mtr[5];
  float bhr_r = 0, bhz_r = 0, bhn_r = 0;
  float wc0 = 0, wc1 = 0, wl0 = 0, wl1 = 0, wl2 = 0;
  float bl0 = 0, bl1 = 0, bl2 = 0, bc0 = 0;
  float wbs0 = 0, wbs1 = 0;
  float kap[5], wg[14], wcB = 0.f;
  float cR = 0.f, cG = 0.f, CXa = 0.f;
  double S0 = 0.0, S1 = 0.0, bb0d = 0.0, bb1d = 0.0;
  double xb0 = 0.0, xb1 = 0.0, gb0 = 0.0, gb1 = 0.0;
  double xb0n = 0.0, xb1n = 0.0, gb0n = 0.0, gb1n = 0.0;
  int dsto = -1;
  int ttk[5], cnk[5], obk[5];
  float wfs[29];
  #pragma unroll
  for (int k = 0; k < 5; ++k) { mtr[k] = 0.f; kap[k] = 0.f; ttk[k] = 0; cnk[k] = 0; obk[k] = 0; }
  #pragma unroll
  for (int j = 0; j < 14; ++j) wg[j] = 0.f;
  #pragma unroll
  for (int k = 0; k < 29; ++k) wfs[k] = 0.f;

  if (tid == 0) nz_sh = 0;
  __syncthreads();
  {
    int any = 0;
    const float4* h4 = (const float4*)hx;
    for (int q = tid; q < (NB * STATE) / 4; q += 256) {
      float4 v = h4[q];
      any |= (v.x != 0.f) | (v.y != 0.f) | (v.z != 0.f) | (v.w != 0.f);
    }
    if (any) nz_sh = 1;
  }
  if (w == 0) {
    #pragma unroll
    for (int k = 0; k < 29; ++k) wfs[k] = Wf[(size_t)lane * WFCOLS + CONVOUT + k];
    bhr_r = bhh[lane]; bhz_r = bhh[64 + lane]; bhn_r = bhh[128 + lane];
    wc0 = Wc[lane]; wc1 = Wc[64 + lane]; bc0 = bc[0];
    wl0 = Wl[lane]; wl1 = Wl[64 + lane]; wl2 = Wl[128 + lane];
    bl0 = bl[0]; bl1 = bl[1]; bl2 = bl[2];
    bb0d = (double)bb[0]; bb1d = (double)bb[1];
    if (lane < 14) { wbs0 = Wb[CONVOUT + lane]; wbs1 = Wb[(size_t)WBCOLS + CONVOUT + lane]; }
    const float* r0 = inp + (size_t)n * DIN + CONVOUT;
    #pragma unroll
    for (int k = 0; k < 5; ++k) {
      int ttv = (int)r0[k], cntv = (int)r0[5 + k] - 1, objv = (int)r0[10 + k];
      ttk[k] = ttv; cnk[k] = cntv; obk[k] = objv;
      float v = 0.f;
      if (lane < 5)       v = (lane == ttv) ? 1.f : 0.f;
      else if (lane < 8)  v = ((lane - 5) == cntv) ? 1.f : 0.f;
      else if (lane < 14) v = ((lane - 8) == objv) ? 1.f : 0.f;
      mtr[k] = v;
      if (lane == 0) { ti_lds[k] = ttv; ti_lds[5 + k] = cntv; ti_lds[10 + k] = objv; }
    }
    // packed state layout: lanes 0-13 r, 14-27 g, 28 b, 29-33 p
    int src = -1;
    if (lane < 14)       { dsto = 5 + lane;          src = dsto; }
    else if (lane < 28)  { dsto = 83 + (lane - 14);  src = dsto; }
    else if (lane == 28) { dsto = 97;                src = 97; }
    else if (lane < 34)  { dsto = lane - 29;         src = dsto; }
    rgbp = (src >= 0) ? hx[(size_t)n * STATE + src] : 0.f;
    hreg = hx[(size_t)n * STATE + 19 + lane];
  }
  __syncthreads();   // nz_sh ready

  if (w == 0) {
    if (nz_sh == 0) {   // new episode: p[0]=1, r=g=M[:,0]
      if (lane == 29) rgbp = 1.f;
      else if (lane < 14) rgbp = mtr[0];
      else if (lane >= 14 && lane < 28) {
        int j = lane - 14;
        rgbp = (j < 5) ? ((j == ttk[0]) ? 1.f : 0.f)
             : (j < 8) ? (((j - 5) == cnk[0]) ? 1.f : 0.f)
                       : (((j - 8) == obk[0]) ? 1.f : 0.f);
      }
    }
    // publish init data
    #pragma unroll
    for (int j = 0; j < 29; ++j) ws_lds[j][lane] = wfs[j];
    if (lane < 28) rg0_lds[lane] = rgbp;           // r0[0..13], g0 at [14..27]
    if (lane == 28) { rg0_lds[28] = rgbp; pub_f[0] = rgbp; }
    h_lds[lane] = hreg;
    if (lane < 6) cp_lds[1][lane] = 0.f;           // parity-1 zeros -> t=0 GI update is identity
    if (lane < 3) pub_i[lane] = 0;
  }
  __syncthreads();   // published

  if (w == 0) {
    // one-time scalars: kap, wg, wcB
    #pragma unroll
    for (int k = 0; k < 5; ++k) {
      float wfrm = SEL5(wfs[0], wfs[1], wfs[2], wfs[3], wfs[4], ttk[k])
                 + SEL3(wfs[5], wfs[6], wfs[7], cnk[k])
                 + SEL6(wfs[8], wfs[9], wfs[10], wfs[11], wfs[12], wfs[13], obk[k]);
      kap[k] = dpp_sum_bcast(wc0 * wfrm);
    }
    #pragma unroll
    for (int j = 0; j < 14; ++j) wg[j] = dpp_sum_bcast(wc0 * wfs[14 + j]);
    wcB = dpp_sum_bcast(wc0 * wfs[28]);
    // cR/cG init from r0/g0
    {
      float rs = 0.f, gs = 0.f;
      #pragma unroll
      for (int j = 0; j < 14; ++j) {
        rs = fmaf(wfs[j], rlane(rgbp, j), rs);
        gs = fmaf(wfs[14 + j], rlane(rgbp, 14 + j), gs);
      }
      cR = dpp_sum_bcast(wc0 * rs);
      cG = dpp_sum_bcast(wc0 * gs);
    }
    // S init (fp64)
    #pragma unroll
    for (int j = 0; j < 14; ++j) {
      double gv = (double)rlane(rgbp, 14 + j);
      S0 += gv * (double)rlane(wbs0, j);
      S1 += gv * (double)rlane(wbs1, j);
    }
    // t=0 prefetches
    CXa = GIx[((size_t)0 * NB + n) * GIXST + 192];
    xb0 = Xb[(size_t)n * 2 + 0]; xb1 = Xb[(size_t)n * 2 + 1];
    gb0 = Gb[(size_t)n * 2 + 0]; gb1 = Gb[(size_t)n * 2 + 1];
    // pq(0): Wl/wc1 dots on h(0)
    float p0 = wl0 * hreg, p1 = wl1 * hreg, p2 = wl2 * hreg, cah = wc1 * hreg;
    dpp_sum4(p0, p1, p2, cah);
    if (lane == 63) { pq_lds[0] = p0; pq_lds[1] = p1; pq_lds[2] = p2; pq_lds[3] = cah; }
  } else {
    // ---- waves: build M_r, M_g, m_b from Wih_s and published Wf columns ----
    float Mr[14];
    #pragma unroll
    for (int j = 0; j < 14; ++j) Mr[j] = 0.f;
    {
      float wsrow[64];
      {
        const f32x2* wr0 = (const f32x2*)&Wih[(size_t)i * 128];
        #pragma unroll
        for (int l2 = 0; l2 < 32; ++l2) { f32x2 v = wr0[l2]; wsrow[2*l2] = v.x; wsrow[2*l2+1] = v.y; }
      }
      #pragma unroll
      for (int l = 0; l < 64; ++l) {
        float wv = wsrow[l];
        #pragma unroll
        for (int j = 0; j < 14; ++j) {
          Mr[j] = fmaf(wv, ws_lds[j][l], Mr[j]);
          Mg[j] = fmaf(wv, ws_lds[14 + j][l], Mg[j]);
        }
        m_b = fmaf(wv, ws_lds[28][l], m_b);
      }
    }
    #pragma unroll
    for (int k = 0; k < 5; ++k) {
      int tt = ti_lds[k], cn = ti_lds[5 + k], ob = ti_lds[10 + k];
      V[k] = SEL5(Mr[0], Mr[1], Mr[2], Mr[3], Mr[4], tt)
           + SEL3(Mr[5], Mr[6], Mr[7], cn)
           + SEL6(Mr[8], Mr[9], Mr[10], Mr[11], Mr[12], Mr[13], ob);
    }
    GI_r = 0.f; GI_g = 0.f;
    #pragma unroll
    for (int j = 0; j < 14; ++j) {
      GI_r = fmaf(Mr[j], rg0_lds[j], GI_r);
      GI_g = fmaf(Mg[j], rg0_lds[14 + j], GI_g);
    }
    // persistent weight rows
    {
      const f32x2* wr = (const f32x2*)&Wih[(size_t)i * 128 + 64];
      #pragma unroll
      for (int k2 = 0; k2 < 32; ++k2) wih_h[k2] = wr[k2];
      bihc = bih[i];
    }
    if (lane < 30) {
      const f32x2* pr = (const f32x2*)&Wpi[(size_t)oi * 78];
      #pragma unroll
      for (int k2 = 0; k2 < 32; ++k2) wpi_p[k2] = pr[k2];
      bpi_r = bpi[oi];
      const float* wp = Wpi + (size_t)oi * 78 + 64;
      #pragma unroll
      for (int k = 0; k < 5; ++k)
        WpiM[k] = wp[ti_lds[k]] + wp[5 + ti_lds[5 + k]] + wp[8 + ti_lds[10 + k]];
      accR = 0.f;
      #pragma unroll
      for (int j = 0; j < 14; ++j) accR = fmaf(wp[j], rg0_lds[j], accR);
      gumA = Gg[(size_t)n * NG + oi];
    }
    gixA = GIx[((size_t)0 * NB + n) * GIXST + i];
    // gih(0) from h(0)
    {
      const f32x2* hp = (const f32x2*)h_lds;
      f32x2 A = {bihc, 0.f}, B = {0.f, 0.f};
      #pragma unroll
      for (int k2 = 0; k2 < 32; k2 += 2) {
        f32x2 h0 = hp[k2], h1 = hp[k2 + 1];
        A.x = fmaf(wih_h[k2].x, h0.x, A.x);
        A.y = fmaf(wih_h[k2].y, h0.y, A.y);
        B.x = fmaf(wih_h[k2 + 1].x, h1.x, B.x);
        B.y = fmaf(wih_h[k2 + 1].y, h1.y, B.y);
      }
      gihreg = (A.x + A.y) + (B.x + B.y);
    }
  }
  __syncthreads();

  const size_t outF = (size_t)T_STEPS * NB * STATE;

  float cg = 0.f;
  double cgd = 0.0;

  #pragma unroll 1
  for (int t = 0; t < T_STEPS; ++t) {
    // ======== P1: wave0 softmax/cg/p/r  ||  waves assemble gi(t) ========
    if (w == 0) {
      float P0 = pq_lds[0] + bl0, P1v = pq_lds[1] + bl1, P2v = pq_lds[2] + bl2;
      float cgaH = pq_lds[3];
      float mx = fmaxf(P0, fmaxf(P1v, P2v));
      float e0 = expf(P0 - mx), e1 = expf(P1v - mx), e2 = expf(P2v - mx);
      float se = e0 + e1 + e2;
      float l0 = e0 / se, l1 = e1 / se, l2 = e2 / se;
      float bprev = rlane(rgbp, 28);
      float cga = CXa + cR + cG + bprev * wcB + cgaH;
      cg = 1.f / (1.f + expf(-(cga + bc0)));
      cgd = (double)cg;
      float pv0 = rlane(rgbp, 29), pv1 = rlane(rgbp, 30), pv2 = rlane(rgbp, 31);
      float pv3 = rlane(rgbp, 32), pv4 = rlane(rgbp, 33);
      float pc0 = pv0 * l1 + pv1 * l2;
      float pc1 = pv0 * l0 + pv1 * l1 + pv2 * l2;
      float pc2 = pv1 * l0 + pv2 * l1 + pv3 * l2;
      float pc3 = pv2 * l0 + pv3 * l1 + pv4 * l2;
      float pc4 = pv3 * l0 + pv4 * l1;
      if (lane >= 29 && lane < 34) {
        float pcl = (lane == 29) ? pc0 : (lane == 30) ? pc1 : (lane == 31) ? pc2
                  : (lane == 32) ? pc3 : pc4;
        rgbp = cg * pcl + (1.f - cg) * rgbp;
      }
      if (lane < 14) {
        float rn2 = pc0 * mtr[0] + pc1 * mtr[1] + pc2 * mtr[2] + pc3 * mtr[3] + pc4 * mtr[4];
        rgbp = cg * rn2 + (1.f - cg) * rgbp;
      }
      cR = cg * (pc0 * kap[0] + pc1 * kap[1] + pc2 * kap[2] + pc3 * kap[3] + pc4 * kap[4])
         + (1.f - cg) * cR;
      if (lane == 0) {
        float* cp = cp_lds[t & 1];
        cp[0] = cg; cp[1] = pc0; cp[2] = pc1; cp[3] = pc2; cp[4] = pc3; cp[5] = pc4;
      }
    } else {
      const float* cp = cp_lds[(t + 1) & 1];
      float cgp = cp[0];
      float rmix = cp[1] * V[0] + cp[2] * V[1] + cp[3] * V[2] + cp[4] * V[3] + cp[5] * V[4];
      GI_r = cgp * rmix + (1.f - cgp) * GI_r;
      int pt1 = pub_i[0], pb1 = pub_i[1], pc1i = pub_i[2];
      float mgs = SEL5(Mg[0], Mg[1], Mg[2], Mg[3], Mg[4], pt1)
                + SEL3(Mg[5], Mg[6], Mg[7], pb1)
                + SEL6(Mg[8], Mg[9], Mg[10], Mg[11], Mg[12], Mg[13], pc1i);
      GI_g = cgp * mgs + (1.f - cgp) * GI_g;
      float bprev = pub_f[0];
      gi_lds[i] = gihreg + gixA + GI_r + GI_g + bprev * m_b;
    }
    bar_lds();   // ---- bar1: gi(t) ready ----

    // ======== P2: wave0 gates/h  ||  waves prefetch t+1 ========
    if (w == 0) {
      float g0 = gi_lds[lane], g1 = gi_lds[64 + lane], g2 = gi_lds[128 + lane];
      float rg = 1.f / (1.f + expf(-(g0 + bhr_r)));
      float z  = 1.f / (1.f + expf(-(g1 + bhz_r)));
      float nn = tanhf(g2 + rg * bhn_r);
      hreg = cg * ((1.f - z) * nn) + (1.f - cg) * hreg;
      h_lds[lane] = hreg;
    } else {
      int tn = (t + 1 < T_STEPS) ? t + 1 : t;
      gixA = GIx[((size_t)tn * NB + n) * GIXST + i];
      if (lane < 30) gumB = Gg[(size_t)tn * NB * NG + (size_t)n * NG + oi];
    }
    bar_lds();   // ---- bar2: h(t) ready ----

    // ======== P3: waves lg+argmax  ||  wave0 dots(t+1) + stores + prefetch ========
    if (w != 0) {
      const float* cp = cp_lds[t & 1];
      float cgc = cp[0];
      float vb = NEGINFF;
      if (lane < 30) {
        float rmx = cp[1] * WpiM[0] + cp[2] * WpiM[1] + cp[3] * WpiM[2]
                  + cp[4] * WpiM[3] + cp[5] * WpiM[4];
        accR = cgc * rmx + (1.f - cgc) * accR;
        const f32x2* hp = (const f32x2*)h_lds;
        f32x2 A = {bpi_r + accR, 0.f}, B = {0.f, 0.f};
        #pragma unroll
        for (int k2 = 0; k2 < 32; k2 += 2) {
          f32x2 h0 = hp[k2], h1 = hp[k2 + 1];
          A.x = fmaf(wpi_p[k2].x, h0.x, A.x);
          A.y = fmaf(wpi_p[k2].y, h0.y, A.y);
          B.x = fmaf(wpi_p[k2 + 1].x, h1.x, B.x);
          B.y = fmaf(wpi_p[k2 + 1].y, h1.y, B.y);
        }
        float lgv = (A.x + A.y) + (B.x + B.y);
        lgst[((size_t)t * NB + n) * NG + oi] = lgv;
        vb = (float)(gumA + (double)lgv);
      }
      gumA = gumB;
      float m1 = vb, m2 = NEGINFF;
      dpp_amax2(m1, m2);
      float M1w = rlane(m1, 63);
      unsigned long long bm = __ballot(vb == M1w);
      int il = __ffsll(bm) - 1;
      if (lane == 63) { pm_lds[w - 1][0] = m1; pm_lds[w - 1][1] = m2; pidx_lds[w - 1] = il; }
    } else {
      float p0 = wl0 * hreg, p1 = wl1 * hreg, p2 = wl2 * hreg, cah = wc1 * hreg;
      dpp_sum4(p0, p1, p2, cah);
      if (lane == 63) { pq_lds[0] = p0; pq_lds[1] = p1; pq_lds[2] = p2; pq_lds[3] = cah; }
      size_t rn = (size_t)t * NB + n;
      float* ob = out + rn * STATE;
      ob[19 + lane] = hreg;
      if (dsto >= 0 && (lane < 14 || lane >= 29)) ob[dsto] = rgbp;   // r, p
      int tn = (t + 1 < T_STEPS) ? t + 1 : t;
      CXa = GIx[((size_t)tn * NB + n) * GIXST + 192];
      xb0n = Xb[((size_t)tn * NB + n) * 2 + 0];
      xb1n = Xb[((size_t)tn * NB + n) * 2 + 1];
      gb0n = Gb[((size_t)tn * NB + n) * 2 + 0];
      gb1n = Gb[((size_t)tn * NB + n) * 2 + 1];
    }
    bar_lds();   // ---- bar3: argmax partials ready ----

    // ======== P4: wave0 combine+sampling  ||  waves gih(t+1) ========
    if (w == 0) {
      float m1a = pm_lds[0][0], m2a = pm_lds[0][1];
      float m1b = pm_lds[1][0], m2b = pm_lds[1][1];
      float m1c = pm_lds[2][0], m2c = pm_lds[2][1];
      float M1 = fmaxf(m1a, fmaxf(m1b, m1c));
      float M2; int gidx;
      if (m1a == M1)      { M2 = fmaxf(m2a, fmaxf(m1b, m1c)); gidx = pidx_lds[0]; }
      else if (m1b == M1) { M2 = fmaxf(m2b, fmaxf(m1a, m1c)); gidx = 30 + pidx_lds[1]; }
      else                { M2 = fmaxf(m2c, fmaxf(m1a, m1b)); gidx = 60 + pidx_lds[2]; }
      if (M1 - M2 < 3e-5f) {
        // rare fp64 slow path: exact recompute from global weights
        double gum0s = Gg[(size_t)t * NB * NG + (size_t)n * NG + lane];
        double gum1s = (lane < 26) ? Gg[(size_t)t * NB * NG + (size_t)n * NG + 64 + lane] : 0.0;
        double e0d = (double)bpi[lane];
        double e1d = (lane < 26) ? (double)bpi[64 + lane] : -1.0e300;
        #pragma unroll 1
        for (int k = 0; k < 64; ++k) {
          double hv2 = (double)rlane(hreg, k);
          e0d = fma((double)Wpi[(size_t)lane * 78 + k], hv2, e0d);
          if (lane < 26) e1d = fma((double)Wpi[(size_t)(64 + lane) * 78 + k], hv2, e1d);
        }
        #pragma unroll 1
        for (int k = 0; k < 14; ++k) {
          double rv = (double)rlane(rgbp, k);
          e0d = fma((double)Wpi[(size_t)lane * 78 + 64 + k], rv, e0d);
          if (lane < 26) e1d = fma((double)Wpi[(size_t)(64 + lane) * 78 + 64 + k], rv, e1d);
        }
        double kk0 = e0d + gum0s;
        double kk1 = (lane < 26) ? e1d + gum1s : -1.0e300;
        double d1; int di;
        if (kk1 > kk0) { d1 = kk1; di = lane + 64; } else { d1 = kk0; di = lane; }
        #pragma unroll
        for (int off = 32; off; off >>= 1) {
          double od = __shfl_xor(d1, off, 64);
          int    oid = __shfl_xor(di, off, 64);
          if (od > d1 || (od == d1 && oid < di)) { d1 = od; di = oid; }
        }
        gidx = di;
      }
      int t1 = gidx / 18, rem = gidx - t1 * 18;
      int b1 = rem / 6, c1 = rem - b1 * 6;
      if (lane >= 14 && lane < 28) {
        int j = lane - 14;
        float ge = (j < 5) ? ((j == t1) ? 1.f : 0.f)
                 : (j < 8) ? (((j - 5) == b1) ? 1.f : 0.f)
                           : (((j - 8) == c1) ? 1.f : 0.f);
        rgbp = cg * ge + (1.f - cg) * rgbp;
      }
      float wgs = SEL5(wg[0], wg[1], wg[2], wg[3], wg[4], t1)
                + SEL3(wg[5], wg[6], wg[7], b1)
                + SEL6(wg[8], wg[9], wg[10], wg[11], wg[12], wg[13], c1);
      cG = cg * wgs + (1.f - cg) * cG;
      double u0 = (double)rlane(wbs0, t1) + (double)rlane(wbs0, 5 + b1) + (double)rlane(wbs0, 8 + c1);
      double u1 = (double)rlane(wbs1, t1) + (double)rlane(wbs1, 5 + b1) + (double)rlane(wbs1, 8 + c1);
      S0 = cgd * u0 + (1.0 - cgd) * S0;
      S1 = cgd * u1 + (1.0 - cgd) * S1;
      double lb0 = xb0 + bb0d + S0;
      double lb1 = xb1 + bb1d + S1;
      int bi = ((lb1 + gb1) > (lb0 + gb0)) ? 1 : 0;
      if (lane == 28) rgbp = (float)bi;
      size_t rn = (size_t)t * NB + n;
      float* ob = out + rn * STATE;
      if (dsto >= 0 && lane >= 14 && lane < 29) ob[dsto] = rgbp;     // g, b
      if (lane == 0) {
        lbst[rn * 2 + 0] = (float)lb0; lbst[rn * 2 + 1] = (float)lb1;
        gidxst[rn] = gidx; bidxst[rn] = bi;
        pub_i[0] = t1; pub_i[1] = b1; pub_i[2] = c1;
      }
      if (lane == 28) pub_f[0] = rgbp;
      if (t == T_STEPS - 1) {
        float* of = out + outF + (size_t)n * STATE;
        if (dsto >= 0) of[dsto] = rgbp;
        of[19 + lane] = hreg;
      }
      xb0 = xb0n; xb1 = xb1n; gb0 = gb0n; gb1 = gb1n;
    } else {
      // gih(t+1) from h(t)
      const f32x2* hp = (const f32x2*)h_lds;
      f32x2 A = {bihc, 0.f}, B = {0.f, 0.f};
      #pragma unroll
      for (int k2 = 0; k2 < 32; k2 += 2) {
        f32x2 h0 = hp[k2], h1 = hp[k2 + 1];
        A.x = fmaf(wih_h[k2].x, h0.x, A.x);
        A.y = fmaf(wih_h[k2].y, h0.y, A.y);
        B.x = fmaf(wih_h[k2 + 1].x, h1.x, B.x);
        B.y = fmaf(wih_h[k2 + 1].y, h1.y, B.y);
      }
      gihreg = (A.x + A.y) + (B.x + B.y);
    }
    bar_lds();   // ---- bar_s: state(t) published ----
  }
}

// ---------------- K4: deferred log-prob (fp32, fully parallel, unchanged) ----------------
__global__ __launch_bounds__(256) void k_lp(const float* __restrict__ lgst,
                                            const float* __restrict__ lbst,
                                            const int* __restrict__ gidxst,
                                            const int* __restrict__ bidxst,
                                            float* __restrict__ out) {
  int tid = threadIdx.x, lane = tid & 63, w = tid >> 6;
  size_t rn = (size_t)blockIdx.x * 4 + w;   // < 16384
  const float* lg = lgst + rn * NG;
  float v0 = lg[lane];
  float v1 = (lane < 26) ? lg[64 + lane] : -3.0e38f;
  float ml = fmaxf(v0, v1);
  #pragma unroll
  for (int off = 32; off; off >>= 1) ml = fmaxf(ml, __shfl_xor(ml, off, 64));
  float e = expf(v0 - ml) + ((lane < 26) ? expf(v1 - ml) : 0.f);
  #pragma unroll
  for (int off = 32; off; off >>= 1) e += __shfl_xor(e, off, 64);
  int gi = gidxst[rn];
  float lpg = (lg[gi] - ml) - logf(e);
  float lb0 = lbst[rn * 2 + 0], lb1 = lbst[rn * 2 + 1];
  int bi = bidxst[rn];
  float mx = fmaxf(lb0, lb1);
  float seb = expf(lb0 - mx) + expf(lb1 - mx);
  float lpb = ((bi ? lb1 : lb0) - mx) - logf(seb);
  if (lane == 0) {
    int t = (int)(rn / NB), n = (int)(rn % NB);
    float lp = lpg + lpb;
    out[rn * STATE + 98] = lp;
    if (t == T_STEPS - 1) out[(size_t)T_STEPS * NB * STATE + (size_t)n * STATE + 98] = lp;
  }
}

// ---------------- launcher ----------------
extern "C" void kernel_launch(void* const* d_in, const int* in_sizes, int n_in,
                              void* d_out, int out_size, void* d_ws, size_t ws_size,
                              hipStream_t stream) {
  const float* inp = (const float*)d_in[0];
  const float* hx  = (const float*)d_in[1];
  const float* Wf  = (const float*)d_in[2];
  const float* bf  = (const float*)d_in[3];
  const float* Wih = (const float*)d_in[4];
  const float* bih = (const float*)d_in[5];
  const float* bhh = (const float*)d_in[6];
  const float* Wc  = (const float*)d_in[7];
  const float* bc  = (const float*)d_in[8];
  const float* Wl  = (const float*)d_in[9];
  const float* bl  = (const float*)d_in[10];
  const float* Wpi = (const float*)d_in[11];
  const float* bpi = (const float*)d_in[12];
  const float* Wb  = (const float*)d_in[13];
  const float* bb  = (const float*)d_in[14];
  float* out = (float*)d_out;

  // ws layout (~35.5 MB, same footprint; dead regions re-aliased):
  double* Gg  = (double*)d_ws;                        // 128*128*90 d
  double* Gb  = Gg + (size_t)T_STEPS * NB * NG;       // 128*128*2 d
  double* Xb  = Gb + (size_t)T_STEPS * NB * 2;        // 16384*2 d
  double* Pd  = Xb + (size_t)NROWS * 2;               // 4*16384*2 d   (dead after k_reduce)
  float*  Wt  = (float*)(Pd + (size_t)4 * NROWS * 2); // 4096*68 f     (dead after k_gemm)
  float*  Wt2 = Wt + (size_t)4096 * 68;               // 64*208 f      (dead after k_gemm2)
  float*  Xf  = Wt2 + (size_t)64 * 208;               // 16384*64 f    (dead after k_gemm2)
  float*  Pf  = Xf + (size_t)NROWS * 64;              // 4*16384*64 f  (dead after k_reduce)
  // GI_x aliases Pf (written by k_gemm2 after k_reduce consumed Pf):
  float*  GIx = Pf;                                   // 16384*193 f <= Pf size
  // lgst group aliases Pd+Wt+Wt2+Xf (all dead before k_scan writes):
  float*  lgst = (float*)Pd;                          // 16384*90 f
  float*  lbst = lgst + (size_t)NROWS * NG;           // 16384*2 f
  int*    gidxst = (int*)(lbst + (size_t)NROWS * 2);  // 16384
  int*    bidxst = gidxst + NROWS;                    // 16384

  k_transpose<<<(66 * 4096) / 256, 256, 0, stream>>>(Wf, Wb, Wt);
  k_tr2<<<(64 * GIXST + 255) / 256, 256, 0, stream>>>(Wih, Wc, Wt2);
  k_gemm<<<1024, 256, 0, stream>>>(inp, Wt, Pf, Pd);
  {
    size_t tot = (size_t)NROWS * 64 + (size_t)NROWS * 2;
    k_reduce<<<(int)((tot + 255) / 256), 256, 0, stream>>>(Pf, Pd, Xf, Xb);
  }
  k_gemm2<<<256, 256, 0, stream>>>(Xf, bf, Wt2, GIx);
  k_noise<<<T_STEPS * 9, 256, 0, stream>>>(Gg, Gb);
  k_scan<<<NB, 256, 0, stream>>>(inp, hx, Wf, Wih, bih, bhh, Wc, bc, Wl, bl,
                                 Wpi, bpi, Wb, bb, GIx, Xb, Gg, Gb,
                                 lgst, lbst, gidxst, bidxst, out);
  k_lp<<<NROWS / 4, 256, 0, stream>>>(lgst, lbst, gidxst, bidxst, out);
}

// Round 6
// 904.581 us; speedup vs baseline: 1.0445x; 1.0398x over previous
//
#include <hip/hip_runtime.h>
#include <stdint.h>
#include <math.h>

// Problem constants (from reference)
#define T_STEPS 128
#define NB      128
#define HID     64
#define CONVOUT 4096
#define NSUB    5
#define SUBSZ   14      // A+B+C = 5+3+6
#define NG      90      // A*B*C
#define STATE   99
#define DIN     4111    // CONVOUT + 3*NSUB
#define WFCOLS  4125    // CONVOUT + 2*SUBSZ + 1
#define WBCOLS  4110    // CONVOUT + SUBSZ
#define NROWS   (T_STEPS * NB)   // 16384
#define GIXST   193              // GI_x row stride (192 gi cols + CX)

#define NEGINFF (-3.0e38f)

typedef __attribute__((ext_vector_type(2))) float f32x2;

#define SEL5(a,b,c,d,e,ix) ((ix)==0?(a):(ix)==1?(b):(ix)==2?(c):(ix)==3?(d):(e))
#define SEL3(a,b,c,ix)     ((ix)==0?(a):(ix)==1?(b):(c))
#define SEL6(a,b,c,d,e,f,ix) ((ix)==0?(a):(ix)==1?(b):(ix)==2?(c):(ix)==3?(d):(ix)==4?(e):(f))

// ---------------- Threefry-2x32 (JAX-compatible) ----------------
__device__ __forceinline__ void tf2x32(unsigned k0, unsigned k1,
                                       unsigned x0, unsigned x1,
                                       unsigned &o0, unsigned &o1) {
  unsigned K0 = k0, K1 = k1, K2 = k0 ^ k1 ^ 0x1BD11BDAu;
  x0 += K0; x1 += K1;
  const int R0[4] = {13, 15, 26, 6};
  const int R1[4] = {17, 29, 16, 24};
  #pragma unroll
  for (int j = 0; j < 4; ++j) { x0 += x1; x1 = (x1 << R0[j]) | (x1 >> (32 - R0[j])); x1 ^= x0; }
  x0 += K1; x1 += K2 + 1u;
  #pragma unroll
  for (int j = 0; j < 4; ++j) { x0 += x1; x1 = (x1 << R1[j]) | (x1 >> (32 - R1[j])); x1 ^= x0; }
  x0 += K2; x1 += K0 + 2u;
  #pragma unroll
  for (int j = 0; j < 4; ++j) { x0 += x1; x1 = (x1 << R0[j]) | (x1 >> (32 - R0[j])); x1 ^= x0; }
  x0 += K0; x1 += K1 + 3u;
  #pragma unroll
  for (int j = 0; j < 4; ++j) { x0 += x1; x1 = (x1 << R1[j]) | (x1 >> (32 - R1[j])); x1 ^= x0; }
  x0 += K1; x1 += K2 + 4u;
  #pragma unroll
  for (int j = 0; j < 4; ++j) { x0 += x1; x1 = (x1 << R0[j]) | (x1 >> (32 - R0[j])); x1 ^= x0; }
  x0 += K2; x1 += K0 + 5u;
  o0 = x0; o1 = x1;
}

__device__ __forceinline__ double bits_to_gumbel_d(unsigned bits) {
  float f = __uint_as_float((bits >> 9) | 0x3f800000u) - 1.0f;   // exact in f32
  const double tiny = (double)1.17549435e-38f;
  double u = fmax(tiny, (double)f + tiny);
  return -log(-log(u));
}

__device__ __forceinline__ float rlane(float v, int l) {
  return __int_as_float(__builtin_amdgcn_readlane(__float_as_int(v), l));
}

// DPP shifted copy: lanes without a source (or rows masked off) get `fill`.
template<int CTRL, int RM>
__device__ __forceinline__ float dpp_mv(float x, float fill) {
  return __int_as_float(__builtin_amdgcn_update_dpp(
      __float_as_int(fill), __float_as_int(x), CTRL, RM, 0xF, false));
}

// 4-way sum reduce (valid at lane 63)
__device__ __forceinline__ void dpp_sum4(float &a, float &b, float &c, float &d) {
  #define S4(C, RM) { a += dpp_mv<C,RM>(a,0.f); b += dpp_mv<C,RM>(b,0.f); \
                      c += dpp_mv<C,RM>(c,0.f); d += dpp_mv<C,RM>(d,0.f); }
  S4(0x111,0xF) S4(0x112,0xF) S4(0x114,0xF) S4(0x118,0xF) S4(0x142,0xA) S4(0x143,0xC)
  #undef S4
}

// (max, runner-up) pair reduce (valid at lane 63)
__device__ __forceinline__ void dpp_amax2(float &m1, float &m2) {
  #define A2(C, RM) { float o1 = dpp_mv<C,RM>(m1,NEGINFF), o2 = dpp_mv<C,RM>(m2,NEGINFF); \
    m2 = fmaxf(fmaxf(m2,o2), fminf(m1,o1)); m1 = fmaxf(m1,o1); }
  A2(0x111,0xF) A2(0x112,0xF) A2(0x114,0xF) A2(0x118,0xF) A2(0x142,0xA) A2(0x143,0xC)
  #undef A2
}

// single sum reduce, broadcast result to all lanes
__device__ __forceinline__ float dpp_sum_bcast(float v) {
  v += dpp_mv<0x111,0xF>(v, 0.f);
  v += dpp_mv<0x112,0xF>(v, 0.f);
  v += dpp_mv<0x114,0xF>(v, 0.f);
  v += dpp_mv<0x118,0xF>(v, 0.f);
  v += dpp_mv<0x142,0xA>(v, 0.f);
  v += dpp_mv<0x143,0xC>(v, 0.f);
  return rlane(v, 63);
}

// Barrier that waits LDS only (lgkmcnt(0)) — does NOT drain vmcnt.
// Raw s_barrier: participation is per-WAVE, so it is legal inside the
// wave-uniform top-level role split as long as barrier COUNTS match.
__device__ __forceinline__ void bar_lds() {
  __asm__ volatile("" ::: "memory");
  __builtin_amdgcn_s_waitcnt(0xC07F);
  __builtin_amdgcn_s_barrier();
  __asm__ volatile("" ::: "memory");
}

// ---------------- K0: pack/transpose weights ----------------
__global__ void k_transpose(const float* __restrict__ Wf, const float* __restrict__ Wb,
                            float* __restrict__ Wt) {
  int idx = blockIdx.x * 256 + threadIdx.x;     // < 66*4096
  int c = idx >> 12;                            // 0..65
  int k = idx & 4095;
  float v = (c < 64) ? Wf[(size_t)c * WFCOLS + k] : Wb[(size_t)(c - 64) * WBCOLS + k];
  Wt[(size_t)k * 68 + c] = v;
}

// ---------------- K0b: Wt2[k][i] = Wih[i][k] (i<192) / Wc[k] (i==192) ----------------
__global__ void k_tr2(const float* __restrict__ Wih, const float* __restrict__ Wc,
                      float* __restrict__ Wt2) {
  int idx = blockIdx.x * 256 + threadIdx.x;
  if (idx >= 64 * GIXST) return;
  int k = idx / GIXST, i = idx - k * GIXST;
  Wt2[(size_t)k * 208 + i] = (i < 192) ? Wih[(size_t)i * 128 + k] : Wc[k];
}

// ---------------- K1: big GEMM, k-split 4 -> partials (unchanged) ----------------
__global__ __launch_bounds__(256, 4) void k_gemm(const float* __restrict__ inp,
                                                 const float* __restrict__ Wt,
                                                 float* __restrict__ Pf,
                                                 double* __restrict__ Pd) {
  __shared__ __align__(16) float xs[64 * 132];
  __shared__ double redd[2][64][2];
  int tid = threadIdx.x;
  int r = tid & 63;
  int w = __builtin_amdgcn_readfirstlane(tid >> 6);
  int rg = blockIdx.x >> 2, kq = blockIdx.x & 3;
  int rowbase = rg * 64;

  float acc[64];
  #pragma unroll
  for (int c = 0; c < 64; ++c) acc[c] = 0.f;
  double ad0 = 0.0, ad1 = 0.0;

  int s_rr[8], s_c4[8];
  #pragma unroll
  for (int i = 0; i < 8; ++i) {
    int idx = tid + i * 256;
    s_rr[i] = idx >> 5;
    s_c4[i] = idx & 31;
  }

  for (int kt = 0; kt < 8; ++kt) {
    int kb = kq * 1024 + kt * 128;
    #pragma unroll
    for (int i = 0; i < 8; ++i) {
      const float* g = inp + (size_t)(rowbase + s_rr[i]) * DIN + kb + s_c4[i] * 4;
      float4 v;
      v.x = g[0]; v.y = g[1]; v.z = g[2]; v.w = g[3];
      *(float4*)&xs[s_rr[i] * 132 + s_c4[i] * 4] = v;
    }
    __syncthreads();
    const float* wkbase = Wt + (size_t)(kb + w * 32) * 68;
    #pragma unroll
    for (int kk = 0; kk < 8; ++kk) {
      float4 xv = *(const float4*)&xs[r * 132 + w * 32 + kk * 4];
      #pragma unroll
      for (int j = 0; j < 4; ++j) {
        float x = (j == 0) ? xv.x : (j == 1) ? xv.y : (j == 2) ? xv.z : xv.w;
        const float* wp = wkbase + (size_t)(kk * 4 + j) * 68;
        #pragma unroll
        for (int c = 0; c < 64; ++c) acc[c] = fmaf(x, wp[c], acc[c]);
        double xd = (double)x;
        ad0 = fma(xd, (double)wp[64], ad0);
        ad1 = fma(xd, (double)wp[65], ad1);
      }
    }
    __syncthreads();
  }

  float* red = xs;
  if (w >= 2) {
    float* d = red + ((size_t)(w - 2) * 64 + r) * 65;
    #pragma unroll
    for (int c = 0; c < 64; ++c) d[c] = acc[c];
    redd[w - 2][r][0] = ad0; redd[w - 2][r][1] = ad1;
  }
  __syncthreads();
  if (w < 2) {
    const float* s = red + ((size_t)w * 64 + r) * 65;
    #pragma unroll
    for (int c = 0; c < 64; ++c) acc[c] += s[c];
    ad0 += redd[w][r][0]; ad1 += redd[w][r][1];
  }
  __syncthreads();
  if (w == 1) {
    float* d = red + (size_t)r * 65;
    #pragma unroll
    for (int c = 0; c < 64; ++c) d[c] = acc[c];
    redd[0][r][0] = ad0; redd[0][r][1] = ad1;
  }
  __syncthreads();
  if (w == 0) {
    const float* s = red + (size_t)r * 65;
    #pragma unroll
    for (int c = 0; c < 64; ++c) acc[c] += s[c];
    ad0 += redd[0][r][0]; ad1 += redd[0][r][1];
    int row = rowbase + r;
    float* po = Pf + (size_t)kq * NROWS * 64 + (size_t)row * 64;
    #pragma unroll
    for (int c = 0; c < 64; ++c) po[c] = acc[c];
    Pd[(size_t)kq * NROWS * 2 + (size_t)row * 2 + 0] = ad0;
    Pd[(size_t)kq * NROWS * 2 + (size_t)row * 2 + 1] = ad1;
  }
}

// ---------------- K1b: reduce the 4 k-quarter partials (unchanged) ----------------
__global__ void k_reduce(const float* __restrict__ Pf, const double* __restrict__ Pd,
                         float* __restrict__ Xf, double* __restrict__ Xb) {
  size_t gid = (size_t)blockIdx.x * 256 + threadIdx.x;
  const size_t NF = (size_t)NROWS * 64;
  if (gid < NF) {
    Xf[gid] = (Pf[gid] + Pf[NF + gid]) + (Pf[2 * NF + gid] + Pf[3 * NF + gid]);
  } else if (gid < NF + (size_t)NROWS * 2) {
    size_t j = gid - NF;
    const size_t ND = (size_t)NROWS * 2;
    Xb[j] = (Pd[j] + Pd[ND + j]) + (Pd[2 * ND + j] + Pd[3 * ND + j]);
  }
}

// ---------------- K1c: GI_x[rn][i] = Wih_s . (Xf[rn]+bf)  (+ CX at col 192) ----------------
__global__ __launch_bounds__(256) void k_gemm2(const float* __restrict__ Xf,
                                               const float* __restrict__ bf,
                                               const float* __restrict__ Wt2,
                                               float* __restrict__ GIx) {
  int tid = threadIdx.x;
  int lane = tid & 63;
  int w = __builtin_amdgcn_readfirstlane(tid >> 6);
  int row = blockIdx.x * 64 + lane;
  int i0 = w * 48;

  float x[64];
  const float* xr = Xf + (size_t)row * 64;
  #pragma unroll
  for (int k4 = 0; k4 < 16; ++k4) {
    float4 xv = *(const float4*)&xr[k4 * 4];
    float4 bv = *(const float4*)&bf[k4 * 4];
    x[k4 * 4 + 0] = xv.x + bv.x;
    x[k4 * 4 + 1] = xv.y + bv.y;
    x[k4 * 4 + 2] = xv.z + bv.z;
    x[k4 * 4 + 3] = xv.w + bv.w;
  }
  float acc[48];
  #pragma unroll
  for (int j = 0; j < 48; ++j) acc[j] = 0.f;
  float acc48 = 0.f;
  for (int k = 0; k < 64; ++k) {
    const float* wp = Wt2 + (size_t)k * 208 + i0;   // wave-uniform -> scalar loads
    float xk = x[k];
    #pragma unroll
    for (int j = 0; j < 48; ++j) acc[j] = fmaf(xk, wp[j], acc[j]);
    if (w == 3) acc48 = fmaf(xk, wp[48], acc48);
  }
  float* o = GIx + (size_t)row * GIXST + i0;
  #pragma unroll
  for (int j = 0; j < 48; ++j) o[j] = acc[j];
  if (w == 3) o[48] = acc48;
}

// ---------------- K2: gumbel noise (JAX partitionable threefry), FP64 ----------------
__global__ void k_noise(double* __restrict__ Gg, double* __restrict__ Gb) {
  int b = blockIdx.x;
  int t = b / 9, c = b - t * 9;
  int tid = threadIdx.x;
  unsigned a, bk, k1a, k1b, k2a, k2b, o0, o1;
  tf2x32(0u, 42u, 0u, (unsigned)t, a, bk);     // keys[t]
  if (c < 8) {
    tf2x32(a, bk, 0u, 0u, k1a, k1b);
    int i0 = c * 1440;                         // 8*1440 = NB*NG
    for (int i = i0 + tid; i < i0 + 1440; i += 256) {
      tf2x32(k1a, k1b, 0u, (unsigned)i, o0, o1);
      Gg[(size_t)t * NB * NG + i] = bits_to_gumbel_d(o0 ^ o1);
    }
  } else {
    tf2x32(a, bk, 0u, 1u, k2a, k2b);
    tf2x32(k2a, k2b, 0u, (unsigned)tid, o0, o1);
    Gb[(size_t)t * NB * 2 + tid] = bits_to_gumbel_d(o0 ^ o1);
  }
}

// ---------------- K3: sequential scan — 4-phase, wave-specialized split ----------------
// Top-level role split: wave0 and waves 1-3 each run their OWN init + t-loop.
// This overlays the two register sets (round-4/5 spilled: both sets live across
// the shared loop -> >256 VGPR -> ~6 dwords/thread/step scratch = +97MB HBM wr).
// Barrier counts match on both paths: 2 init + 4 per step.
__global__ __launch_bounds__(256, 1) void k_scan(
    const float* __restrict__ inp, const float* __restrict__ hx,
    const float* __restrict__ Wf,
    const float* __restrict__ Wih, const float* __restrict__ bih,
    const float* __restrict__ bhh, const float* __restrict__ Wc,
    const float* __restrict__ bc, const float* __restrict__ Wl,
    const float* __restrict__ bl, const float* __restrict__ Wpi,
    const float* __restrict__ bpi, const float* __restrict__ Wb,
    const float* __restrict__ bb,
    const float* __restrict__ GIx, const double* __restrict__ Xb,
    const double* __restrict__ Gg, const double* __restrict__ Gb,
    float* __restrict__ lgst, float* __restrict__ lbst,
    int* __restrict__ gidxst, int* __restrict__ bidxst,
    float* __restrict__ out) {
  const int n = blockIdx.x;
  const int tid = threadIdx.x;
  const int lane = tid & 63;
  const int w = __builtin_amdgcn_readfirstlane(tid >> 6);

  __shared__ __align__(16) float h_lds[64];
  __shared__ __align__(16) float gi_lds[192];
  __shared__ float pq_lds[4];        // Wl0.h, Wl1.h, Wl2.h, wc1.h (wave0-internal)
  __shared__ float cp_lds[2][8];     // [parity]: cg, pc0..4
  __shared__ float pm_lds[3][2];     // per-wave (m1, m2)
  __shared__ int   pidx_lds[3];
  __shared__ int   pub_i[4];         // t1, b1, c1 of prev step
  __shared__ float pub_f[2];         // b(prev) as float
  __shared__ float ws_lds[29][64];   // Wf state cols (init only)
  __shared__ float rg0_lds[32];      // r0[14], g0[14], b0
  __shared__ int   ti_lds[16];       // tt[5], cnt[5], obj[5]

  const size_t outF = (size_t)T_STEPS * NB * STATE;

  if (w == 0) {
    // ================= WAVE 0: state owner =================
    float rgbp = 0.f, hreg = 0.f;
    float mtr[5];
    float bhr_r, bhz_r, bhn_r;
    float wc0, wc1, wl0, wl1, wl2;
    float bl0, bl1, bl2, bc0;
    float wbs0 = 0.f, wbs1 = 0.f;
    float kap[5], wg[14], wcB;
    float cR, cG, CXa;
    double S0 = 0.0, S1 = 0.0, bb0d, bb1d;
    double xb0, xb1, gb0, gb1;
    double xb0n, xb1n, gb0n, gb1n;
    int dsto = -1;
    int ttk[5], cnk[5], obk[5];
    float wfs[29];

    // nz = (hx != all-zero), wave0-local
    bool nz;
    {
      int any = 0;
      const float4* h4 = (const float4*)hx;
      for (int q = lane; q < (NB * STATE) / 4; q += 64) {
        float4 v = h4[q];
        any |= (v.x != 0.f) | (v.y != 0.f) | (v.z != 0.f) | (v.w != 0.f);
      }
      nz = (__ballot(any) != 0ULL);
    }
    #pragma unroll
    for (int k = 0; k < 29; ++k) wfs[k] = Wf[(size_t)lane * WFCOLS + CONVOUT + k];
    bhr_r = bhh[lane]; bhz_r = bhh[64 + lane]; bhn_r = bhh[128 + lane];
    wc0 = Wc[lane]; wc1 = Wc[64 + lane]; bc0 = bc[0];
    wl0 = Wl[lane]; wl1 = Wl[64 + lane]; wl2 = Wl[128 + lane];
    bl0 = bl[0]; bl1 = bl[1]; bl2 = bl[2];
    bb0d = (double)bb[0]; bb1d = (double)bb[1];
    if (lane < 14) { wbs0 = Wb[CONVOUT + lane]; wbs1 = Wb[(size_t)WBCOLS + CONVOUT + lane]; }
    {
      const float* r0 = inp + (size_t)n * DIN + CONVOUT;
      #pragma unroll
      for (int k = 0; k < 5; ++k) {
        int ttv = (int)r0[k], cntv = (int)r0[5 + k] - 1, objv = (int)r0[10 + k];
        ttk[k] = ttv; cnk[k] = cntv; obk[k] = objv;
        float v = 0.f;
        if (lane < 5)       v = (lane == ttv) ? 1.f : 0.f;
        else if (lane < 8)  v = ((lane - 5) == cntv) ? 1.f : 0.f;
        else if (lane < 14) v = ((lane - 8) == objv) ? 1.f : 0.f;
        mtr[k] = v;
        if (lane == 0) { ti_lds[k] = ttv; ti_lds[5 + k] = cntv; ti_lds[10 + k] = objv; }
      }
    }
    // packed state layout: lanes 0-13 r, 14-27 g, 28 b, 29-33 p
    {
      int src = -1;
      if (lane < 14)       { dsto = 5 + lane;          src = dsto; }
      else if (lane < 28)  { dsto = 83 + (lane - 14);  src = dsto; }
      else if (lane == 28) { dsto = 97;                src = 97; }
      else if (lane < 34)  { dsto = lane - 29;         src = dsto; }
      rgbp = (src >= 0) ? hx[(size_t)n * STATE + src] : 0.f;
      hreg = hx[(size_t)n * STATE + 19 + lane];
    }
    if (!nz) {   // new episode: p[0]=1, r=g=M[:,0]
      if (lane == 29) rgbp = 1.f;
      else if (lane < 14) rgbp = mtr[0];
      else if (lane >= 14 && lane < 28) {
        int j = lane - 14;
        rgbp = (j < 5) ? ((j == ttk[0]) ? 1.f : 0.f)
             : (j < 8) ? (((j - 5) == cnk[0]) ? 1.f : 0.f)
                       : (((j - 8) == obk[0]) ? 1.f : 0.f);
      }
    }
    // publish init data for waves
    #pragma unroll
    for (int j = 0; j < 29; ++j) ws_lds[j][lane] = wfs[j];
    if (lane < 28) rg0_lds[lane] = rgbp;
    if (lane == 28) { rg0_lds[28] = rgbp; pub_f[0] = rgbp; }
    h_lds[lane] = hreg;
    if (lane < 6) cp_lds[1][lane] = 0.f;   // parity-1 zeros -> t=0 GI update is identity
    if (lane < 3) pub_i[lane] = 0;

    bar_lds();   // ==== B1: publish done ====

    // one-time scalars
    #pragma unroll
    for (int k = 0; k < 5; ++k) {
      float wfrm = SEL5(wfs[0], wfs[1], wfs[2], wfs[3], wfs[4], ttk[k])
                 + SEL3(wfs[5], wfs[6], wfs[7], cnk[k])
                 + SEL6(wfs[8], wfs[9], wfs[10], wfs[11], wfs[12], wfs[13], obk[k]);
      kap[k] = dpp_sum_bcast(wc0 * wfrm);
    }
    #pragma unroll
    for (int j = 0; j < 14; ++j) wg[j] = dpp_sum_bcast(wc0 * wfs[14 + j]);
    wcB = dpp_sum_bcast(wc0 * wfs[28]);
    {
      float rs = 0.f, gs = 0.f;
      #pragma unroll
      for (int j = 0; j < 14; ++j) {
        rs = fmaf(wfs[j], rlane(rgbp, j), rs);
        gs = fmaf(wfs[14 + j], rlane(rgbp, 14 + j), gs);
      }
      cR = dpp_sum_bcast(wc0 * rs);
      cG = dpp_sum_bcast(wc0 * gs);
    }
    #pragma unroll
    for (int j = 0; j < 14; ++j) {
      double gv = (double)rlane(rgbp, 14 + j);
      S0 += gv * (double)rlane(wbs0, j);
      S1 += gv * (double)rlane(wbs1, j);
    }
    CXa = GIx[((size_t)0 * NB + n) * GIXST + 192];
    xb0 = Xb[(size_t)n * 2 + 0]; xb1 = Xb[(size_t)n * 2 + 1];
    gb0 = Gb[(size_t)n * 2 + 0]; gb1 = Gb[(size_t)n * 2 + 1];
    xb0n = xb0; xb1n = xb1; gb0n = gb0; gb1n = gb1;
    {
      float p0 = wl0 * hreg, p1 = wl1 * hreg, p2 = wl2 * hreg, cah = wc1 * hreg;
      dpp_sum4(p0, p1, p2, cah);
      if (lane == 63) { pq_lds[0] = p0; pq_lds[1] = p1; pq_lds[2] = p2; pq_lds[3] = cah; }
    }

    bar_lds();   // ==== B2 ====

    float cg = 0.f;
    double cgd = 0.0;

    #pragma unroll 1
    for (int t = 0; t < T_STEPS; ++t) {
      // ======== P1: softmax/cg/p/r ========
      {
        float P0 = pq_lds[0] + bl0, P1v = pq_lds[1] + bl1, P2v = pq_lds[2] + bl2;
        float cgaH = pq_lds[3];
        float mx = fmaxf(P0, fmaxf(P1v, P2v));
        float e0 = expf(P0 - mx), e1 = expf(P1v - mx), e2 = expf(P2v - mx);
        float se = e0 + e1 + e2;
        float l0 = e0 / se, l1 = e1 / se, l2 = e2 / se;
        float bprev = rlane(rgbp, 28);
        float cga = CXa + cR + cG + bprev * wcB + cgaH;
        cg = 1.f / (1.f + expf(-(cga + bc0)));
        cgd = (double)cg;
        float pv0 = rlane(rgbp, 29), pv1 = rlane(rgbp, 30), pv2 = rlane(rgbp, 31);
        float pv3 = rlane(rgbp, 32), pv4 = rlane(rgbp, 33);
        float pc0 = pv0 * l1 + pv1 * l2;
        float pc1 = pv0 * l0 + pv1 * l1 + pv2 * l2;
        float pc2 = pv1 * l0 + pv2 * l1 + pv3 * l2;
        float pc3 = pv2 * l0 + pv3 * l1 + pv4 * l2;
        float pc4 = pv3 * l0 + pv4 * l1;
        if (lane >= 29 && lane < 34) {
          float pcl = (lane == 29) ? pc0 : (lane == 30) ? pc1 : (lane == 31) ? pc2
                    : (lane == 32) ? pc3 : pc4;
          rgbp = cg * pcl + (1.f - cg) * rgbp;
        }
        if (lane < 14) {
          float rn2 = pc0 * mtr[0] + pc1 * mtr[1] + pc2 * mtr[2] + pc3 * mtr[3] + pc4 * mtr[4];
          rgbp = cg * rn2 + (1.f - cg) * rgbp;
        }
        cR = cg * (pc0 * kap[0] + pc1 * kap[1] + pc2 * kap[2] + pc3 * kap[3] + pc4 * kap[4])
           + (1.f - cg) * cR;
        if (lane == 0) {
          float* cp = cp_lds[t & 1];
          cp[0] = cg; cp[1] = pc0; cp[2] = pc1; cp[3] = pc2; cp[4] = pc3; cp[5] = pc4;
        }
      }
      bar_lds();   // ---- bar1: gi(t) ready (waves wrote it) ----

      // ======== P2: gates/h ========
      {
        float g0 = gi_lds[lane], g1 = gi_lds[64 + lane], g2 = gi_lds[128 + lane];
        float rg = 1.f / (1.f + expf(-(g0 + bhr_r)));
        float z  = 1.f / (1.f + expf(-(g1 + bhz_r)));
        float nn = tanhf(g2 + rg * bhn_r);
        hreg = cg * ((1.f - z) * nn) + (1.f - cg) * hreg;
        h_lds[lane] = hreg;
      }
      bar_lds();   // ---- bar2: h(t) ready ----

      // ======== P3: dots(t+1) + stores + prefetch ========
      {
        float p0 = wl0 * hreg, p1 = wl1 * hreg, p2 = wl2 * hreg, cah = wc1 * hreg;
        dpp_sum4(p0, p1, p2, cah);
        if (lane == 63) { pq_lds[0] = p0; pq_lds[1] = p1; pq_lds[2] = p2; pq_lds[3] = cah; }
        size_t rn = (size_t)t * NB + n;
        float* ob = out + rn * STATE;
        ob[19 + lane] = hreg;
        if (dsto >= 0 && (lane < 14 || lane >= 29)) ob[dsto] = rgbp;   // r, p
        int tn = (t + 1 < T_STEPS) ? t + 1 : t;
        CXa = GIx[((size_t)tn * NB + n) * GIXST + 192];
        xb0n = Xb[((size_t)tn * NB + n) * 2 + 0];
        xb1n = Xb[((size_t)tn * NB + n) * 2 + 1];
        gb0n = Gb[((size_t)tn * NB + n) * 2 + 0];
        gb1n = Gb[((size_t)tn * NB + n) * 2 + 1];
      }
      bar_lds();   // ---- bar3: argmax partials ready ----

      // ======== P4: combine + sampling ========
      {
        float m1a = pm_lds[0][0], m2a = pm_lds[0][1];
        float m1b = pm_lds[1][0], m2b = pm_lds[1][1];
        float m1c = pm_lds[2][0], m2c = pm_lds[2][1];
        float M1 = fmaxf(m1a, fmaxf(m1b, m1c));
        float M2; int gidx;
        if (m1a == M1)      { M2 = fmaxf(m2a, fmaxf(m1b, m1c)); gidx = pidx_lds[0]; }
        else if (m1b == M1) { M2 = fmaxf(m2b, fmaxf(m1a, m1c)); gidx = 30 + pidx_lds[1]; }
        else                { M2 = fmaxf(m2c, fmaxf(m1a, m1b)); gidx = 60 + pidx_lds[2]; }
        if (M1 - M2 < 3e-5f) {
          // rare fp64 slow path: exact recompute from global weights
          double gum0s = Gg[(size_t)t * NB * NG + (size_t)n * NG + lane];
          double gum1s = (lane < 26) ? Gg[(size_t)t * NB * NG + (size_t)n * NG + 64 + lane] : 0.0;
          double e0d = (double)bpi[lane];
          double e1d = (lane < 26) ? (double)bpi[64 + lane] : -1.0e300;
          #pragma unroll 1
          for (int k = 0; k < 64; ++k) {
            double hv2 = (double)rlane(hreg, k);
            e0d = fma((double)Wpi[(size_t)lane * 78 + k], hv2, e0d);
            if (lane < 26) e1d = fma((double)Wpi[(size_t)(64 + lane) * 78 + k], hv2, e1d);
          }
          #pragma unroll 1
          for (int k = 0; k < 14; ++k) {
            double rv = (double)rlane(rgbp, k);
            e0d = fma((double)Wpi[(size_t)lane * 78 + 64 + k], rv, e0d);
            if (lane < 26) e1d = fma((double)Wpi[(size_t)(64 + lane) * 78 + 64 + k], rv, e1d);
          }
          double kk0 = e0d + gum0s;
          double kk1 = (lane < 26) ? e1d + gum1s : -1.0e300;
          double d1; int di;
          if (kk1 > kk0) { d1 = kk1; di = lane + 64; } else { d1 = kk0; di = lane; }
          #pragma unroll
          for (int off = 32; off; off >>= 1) {
            double od = __shfl_xor(d1, off, 64);
            int    oid = __shfl_xor(di, off, 64);
            if (od > d1 || (od == d1 && oid < di)) { d1 = od; di = oid; }
          }
          gidx = di;
        }
        int t1 = gidx / 18, rem = gidx - t1 * 18;
        int b1 = rem / 6, c1 = rem - b1 * 6;
        if (lane >= 14 && lane < 28) {
          int j = lane - 14;
          float ge = (j < 5) ? ((j == t1) ? 1.f : 0.f)
                   : (j < 8) ? (((j - 5) == b1) ? 1.f : 0.f)
                             : (((j - 8) == c1) ? 1.f : 0.f);
          rgbp = cg * ge + (1.f - cg) * rgbp;
        }
        float wgs = SEL5(wg[0], wg[1], wg[2], wg[3], wg[4], t1)
                  + SEL3(wg[5], wg[6], wg[7], b1)
                  + SEL6(wg[8], wg[9], wg[10], wg[11], wg[12], wg[13], c1);
        cG = cg * wgs + (1.f - cg) * cG;
        double u0 = (double)rlane(wbs0, t1) + (double)rlane(wbs0, 5 + b1) + (double)rlane(wbs0, 8 + c1);
        double u1 = (double)rlane(wbs1, t1) + (double)rlane(wbs1, 5 + b1) + (double)rlane(wbs1, 8 + c1);
        S0 = cgd * u0 + (1.0 - cgd) * S0;
        S1 = cgd * u1 + (1.0 - cgd) * S1;
        double lb0 = xb0 + bb0d + S0;
        double lb1 = xb1 + bb1d + S1;
        int bi = ((lb1 + gb1) > (lb0 + gb0)) ? 1 : 0;
        if (lane == 28) rgbp = (float)bi;
        size_t rn = (size_t)t * NB + n;
        float* ob = out + rn * STATE;
        if (dsto >= 0 && lane >= 14 && lane < 29) ob[dsto] = rgbp;     // g, b
        if (lane == 0) {
          lbst[rn * 2 + 0] = (float)lb0; lbst[rn * 2 + 1] = (float)lb1;
          gidxst[rn] = gidx; bidxst[rn] = bi;
          pub_i[0] = t1; pub_i[1] = b1; pub_i[2] = c1;
        }
        if (lane == 28) pub_f[0] = rgbp;
        if (t == T_STEPS - 1) {
          float* of = out + outF + (size_t)n * STATE;
          if (dsto >= 0) of[dsto] = rgbp;
          of[19 + lane] = hreg;
        }
        xb0 = xb0n; xb1 = xb1n; gb0 = gb0n; gb1 = gb1n;
      }
      bar_lds();   // ---- bar4: state(t) published ----
    }
  } else {
    // ================= WAVES 1-3: gi / lg engines =================
    const int i = tid - 64;                // [0,192)
    const int oi = (w - 1) * 30 + lane;    // lg output index (lane<30)

    f32x2 wih_h[32];                       // Wih[i][64..127]
    f32x2 wpi_p[32];                       // Wpi[oi][0..63] (lane<30)
    float bihc, bpi_r = 0.f;
    float Mg[14], V[5], WpiM[5];
    float m_b = 0.f, GI_r = 0.f, GI_g = 0.f, accR = 0.f, gihreg;
    float gixA;
    double gumA = 0.0, gumB = 0.0;
    #pragma unroll
    for (int j = 0; j < 14; ++j) Mg[j] = 0.f;
    #pragma unroll
    for (int k = 0; k < 5; ++k) WpiM[k] = 0.f;

    bar_lds();   // ==== B1: wait for wave0 publish ====

    // build M_r, M_g, m_b from Wih_s and published Wf columns
    {
      float Mr[14];
      #pragma unroll
      for (int j = 0; j < 14; ++j) Mr[j] = 0.f;
      {
        float wsrow[64];
        {
          const f32x2* wr0 = (const f32x2*)&Wih[(size_t)i * 128];
          #pragma unroll
          for (int l2 = 0; l2 < 32; ++l2) { f32x2 v = wr0[l2]; wsrow[2*l2] = v.x; wsrow[2*l2+1] = v.y; }
        }
        #pragma unroll
        for (int l = 0; l < 64; ++l) {
          float wv = wsrow[l];
          #pragma unroll
          for (int j = 0; j < 14; ++j) {
            Mr[j] = fmaf(wv, ws_lds[j][l], Mr[j]);
            Mg[j] = fmaf(wv, ws_lds[14 + j][l], Mg[j]);
          }
          m_b = fmaf(wv, ws_lds[28][l], m_b);
        }
      }
      #pragma unroll
      for (int k = 0; k < 5; ++k) {
        int tt = ti_lds[k], cn = ti_lds[5 + k], ob = ti_lds[10 + k];
        V[k] = SEL5(Mr[0], Mr[1], Mr[2], Mr[3], Mr[4], tt)
             + SEL3(Mr[5], Mr[6], Mr[7], cn)
             + SEL6(Mr[8], Mr[9], Mr[10], Mr[11], Mr[12], Mr[13], ob);
      }
      GI_r = 0.f; GI_g = 0.f;
      #pragma unroll
      for (int j = 0; j < 14; ++j) {
        GI_r = fmaf(Mr[j], rg0_lds[j], GI_r);
        GI_g = fmaf(Mg[j], rg0_lds[14 + j], GI_g);
      }
    }
    // persistent weight rows
    {
      const f32x2* wr = (const f32x2*)&Wih[(size_t)i * 128 + 64];
      #pragma unroll
      for (int k2 = 0; k2 < 32; ++k2) wih_h[k2] = wr[k2];
      bihc = bih[i];
    }
    if (lane < 30) {
      const f32x2* pr = (const f32x2*)&Wpi[(size_t)oi * 78];
      #pragma unroll
      for (int k2 = 0; k2 < 32; ++k2) wpi_p[k2] = pr[k2];
      bpi_r = bpi[oi];
      const float* wp = Wpi + (size_t)oi * 78 + 64;
      #pragma unroll
      for (int k = 0; k < 5; ++k)
        WpiM[k] = wp[ti_lds[k]] + wp[5 + ti_lds[5 + k]] + wp[8 + ti_lds[10 + k]];
      accR = 0.f;
      #pragma unroll
      for (int j = 0; j < 14; ++j) accR = fmaf(wp[j], rg0_lds[j], accR);
      gumA = Gg[(size_t)n * NG + oi];
    }
    gixA = GIx[((size_t)0 * NB + n) * GIXST + i];
    // gih(0) from h(0)
    {
      const f32x2* hp = (const f32x2*)h_lds;
      f32x2 A = {bihc, 0.f}, B = {0.f, 0.f};
      #pragma unroll
      for (int k2 = 0; k2 < 32; k2 += 2) {
        f32x2 h0 = hp[k2], h1 = hp[k2 + 1];
        A.x = fmaf(wih_h[k2].x, h0.x, A.x);
        A.y = fmaf(wih_h[k2].y, h0.y, A.y);
        B.x = fmaf(wih_h[k2 + 1].x, h1.x, B.x);
        B.y = fmaf(wih_h[k2 + 1].y, h1.y, B.y);
      }
      gihreg = (A.x + A.y) + (B.x + B.y);
    }

    bar_lds();   // ==== B2 ====

    #pragma unroll 1
    for (int t = 0; t < T_STEPS; ++t) {
      // ======== P1': assemble gi(t) ========
      {
        const float* cp = cp_lds[(t + 1) & 1];
        float cgp = cp[0];
        float rmix = cp[1] * V[0] + cp[2] * V[1] + cp[3] * V[2] + cp[4] * V[3] + cp[5] * V[4];
        GI_r = cgp * rmix + (1.f - cgp) * GI_r;
        int pt1 = pub_i[0], pb1 = pub_i[1], pc1i = pub_i[2];
        float mgs = SEL5(Mg[0], Mg[1], Mg[2], Mg[3], Mg[4], pt1)
                  + SEL3(Mg[5], Mg[6], Mg[7], pb1)
                  + SEL6(Mg[8], Mg[9], Mg[10], Mg[11], Mg[12], Mg[13], pc1i);
        GI_g = cgp * mgs + (1.f - cgp) * GI_g;
        float bprev = pub_f[0];
        gi_lds[i] = gihreg + gixA + GI_r + GI_g + bprev * m_b;
      }
      bar_lds();   // ---- bar1 ----

      // ======== P2': prefetch t+1 ========
      {
        int tn = (t + 1 < T_STEPS) ? t + 1 : t;
        gixA = GIx[((size_t)tn * NB + n) * GIXST + i];
        if (lane < 30) gumB = Gg[(size_t)tn * NB * NG + (size_t)n * NG + oi];
      }
      bar_lds();   // ---- bar2: h(t) ready ----

      // ======== P3': lg + argmax ========
      {
        const float* cp = cp_lds[t & 1];
        float cgc = cp[0];
        float vb = NEGINFF;
        if (lane < 30) {
          float rmx = cp[1] * WpiM[0] + cp[2] * WpiM[1] + cp[3] * WpiM[2]
                    + cp[4] * WpiM[3] + cp[5] * WpiM[4];
          accR = cgc * rmx + (1.f - cgc) * accR;
          const f32x2* hp = (const f32x2*)h_lds;
          f32x2 A = {bpi_r + accR, 0.f}, B = {0.f, 0.f};
          #pragma unroll
          for (int k2 = 0; k2 < 32; k2 += 2) {
            f32x2 h0 = hp[k2], h1 = hp[k2 + 1];
            A.x = fmaf(wpi_p[k2].x, h0.x, A.x);
            A.y = fmaf(wpi_p[k2].y, h0.y, A.y);
            B.x = fmaf(wpi_p[k2 + 1].x, h1.x, B.x);
            B.y = fmaf(wpi_p[k2 + 1].y, h1.y, B.y);
          }
          float lgv = (A.x + A.y) + (B.x + B.y);
          lgst[((size_t)t * NB + n) * NG + oi] = lgv;
          vb = (float)(gumA + (double)lgv);
        }
        gumA = gumB;
        float m1 = vb, m2 = NEGINFF;
        dpp_amax2(m1, m2);
        float M1w = rlane(m1, 63);
        unsigned long long bm = __ballot(vb == M1w);
        int il = __ffsll(bm) - 1;
        if (lane == 63) { pm_lds[w - 1][0] = m1; pm_lds[w - 1][1] = m2; pidx_lds[w - 1] = il; }
      }
      bar_lds();   // ---- bar3 ----

      // ======== P4': gih(t+1) from h(t) ========
      {
        const f32x2* hp = (const f32x2*)h_lds;
        f32x2 A = {bihc, 0.f}, B = {0.f, 0.f};
        #pragma unroll
        for (int k2 = 0; k2 < 32; k2 += 2) {
          f32x2 h0 = hp[k2], h1 = hp[k2 + 1];
          A.x = fmaf(wih_h[k2].x, h0.x, A.x);
          A.y = fmaf(wih_h[k2].y, h0.y, A.y);
          B.x = fmaf(wih_h[k2 + 1].x, h1.x, B.x);
          B.y = fmaf(wih_h[k2 + 1].y, h1.y, B.y);
        }
        gihreg = (A.x + A.y) + (B.x + B.y);
      }
      bar_lds();   // ---- bar4 ----
    }
  }
}

// ---------------- K4: deferred log-prob (fp32, fully parallel, unchanged) ----------------
__global__ __launch_bounds__(256) void k_lp(const float* __restrict__ lgst,
                                            const float* __restrict__ lbst,
                                            const int* __restrict__ gidxst,
                                            const int* __restrict__ bidxst,
                                            float* __restrict__ out) {
  int tid = threadIdx.x, lane = tid & 63, w = tid >> 6;
  size_t rn = (size_t)blockIdx.x * 4 + w;   // < 16384
  const float* lg = lgst + rn * NG;
  float v0 = lg[lane];
  float v1 = (lane < 26) ? lg[64 + lane] : -3.0e38f;
  float ml = fmaxf(v0, v1);
  #pragma unroll
  for (int off = 32; off; off >>= 1) ml = fmaxf(ml, __shfl_xor(ml, off, 64));
  float e = expf(v0 - ml) + ((lane < 26) ? expf(v1 - ml) : 0.f);
  #pragma unroll
  for (int off = 32; off; off >>= 1) e += __shfl_xor(e, off, 64);
  int gi = gidxst[rn];
  float lpg = (lg[gi] - ml) - logf(e);
  float lb0 = lbst[rn * 2 + 0], lb1 = lbst[rn * 2 + 1];
  int bi = bidxst[rn];
  float mx = fmaxf(lb0, lb1);
  float seb = expf(lb0 - mx) + expf(lb1 - mx);
  float lpb = ((bi ? lb1 : lb0) - mx) - logf(seb);
  if (lane == 0) {
    int t = (int)(rn / NB), n = (int)(rn % NB);
    float lp = lpg + lpb;
    out[rn * STATE + 98] = lp;
    if (t == T_STEPS - 1) out[(size_t)T_STEPS * NB * STATE + (size_t)n * STATE + 98] = lp;
  }
}

// ---------------- launcher ----------------
extern "C" void kernel_launch(void* const* d_in, const int* in_sizes, int n_in,
                              void* d_out, int out_size, void* d_ws, size_t ws_size,
                              hipStream_t stream) {
  const float* inp = (const float*)d_in[0];
  const float* hx  = (const float*)d_in[1];
  const float* Wf  = (const float*)d_in[2];
  const float* bf  = (const float*)d_in[3];
  const float* Wih = (const float*)d_in[4];
  const float* bih = (const float*)d_in[5];
  const float* bhh = (const float*)d_in[6];
  const float* Wc  = (const float*)d_in[7];
  const float* bc  = (const float*)d_in[8];
  const float* Wl  = (const float*)d_in[9];
  const float* bl  = (const float*)d_in[10];
  const float* Wpi = (const float*)d_in[11];
  const float* bpi = (const float*)d_in[12];
  const float* Wb  = (const float*)d_in[13];
  const float* bb  = (const float*)d_in[14];
  float* out = (float*)d_out;

  // ws layout (~35.5 MB, same footprint; dead regions re-aliased):
  double* Gg  = (double*)d_ws;                        // 128*128*90 d
  double* Gb  = Gg + (size_t)T_STEPS * NB * NG;       // 128*128*2 d
  double* Xb  = Gb + (size_t)T_STEPS * NB * 2;        // 16384*2 d
  double* Pd  = Xb + (size_t)NROWS * 2;               // 4*16384*2 d   (dead after k_reduce)
  float*  Wt  = (float*)(Pd + (size_t)4 * NROWS * 2); // 4096*68 f     (dead after k_gemm)
  float*  Wt2 = Wt + (size_t)4096 * 68;               // 64*208 f      (dead after k_gemm2)
  float*  Xf  = Wt2 + (size_t)64 * 208;               // 16384*64 f    (dead after k_gemm2)
  float*  Pf  = Xf + (size_t)NROWS * 64;              // 4*16384*64 f  (dead after k_reduce)
  // GI_x aliases Pf (written by k_gemm2 after k_reduce consumed Pf):
  float*  GIx = Pf;                                   // 16384*193 f <= Pf size
  // lgst group aliases Pd+Wt+Wt2+Xf (all dead before k_scan writes):
  float*  lgst = (float*)Pd;                          // 16384*90 f
  float*  lbst = lgst + (size_t)NROWS * NG;           // 16384*2 f
  int*    gidxst = (int*)(lbst + (size_t)NROWS * 2);  // 16384
  int*    bidxst = gidxst + NROWS;                    // 16384

  k_transpose<<<(66 * 4096) / 256, 256, 0, stream>>>(Wf, Wb, Wt);
  k_tr2<<<(64 * GIXST + 255) / 256, 256, 0, stream>>>(Wih, Wc, Wt2);
  k_gemm<<<1024, 256, 0, stream>>>(inp, Wt, Pf, Pd);
  {
    size_t tot = (size_t)NROWS * 64 + (size_t)NROWS * 2;
    k_reduce<<<(int)((tot + 255) / 256), 256, 0, stream>>>(Pf, Pd, Xf, Xb);
  }
  k_gemm2<<<256, 256, 0, stream>>>(Xf, bf, Wt2, GIx);
  k_noise<<<T_STEPS * 9, 256, 0, stream>>>(Gg, Gb);
  k_scan<<<NB, 256, 0, stream>>>(inp, hx, Wf, Wih, bih, bhh, Wc, bc, Wl, bl,
                                 Wpi, bpi, Wb, bb, GIx, Xb, Gg, Gb,
                                 lgst, lbst, gidxst, bidxst, out);
  k_lp<<<NROWS / 4, 256, 0, stream>>>(lgst, lbst, gidxst, bidxst, out);
}